// Round 1
// baseline (2133.784 us; speedup 1.0000x reference)
//
#include <hip/hip_runtime.h>
#include <math.h>

// Problem constants
constexpr int kD   = 256;   // model dim
constexpr int kH   = 4;     // heads
constexpr int kHD  = 64;    // head dim
constexpr int kB   = 2;
constexpr int kN   = 6;     // views
constexpr int kM   = 512;   // keypoints (M == NS)
constexpr int kRows = kB*kN*kM;        // 6144 token rows
constexpr int kGrp  = kB*kN*kH;        // 48 attention groups
constexpr size_t kEncSlab = (size_t)kN*kM*kHD;   // 196608 (t/s/k encodings)
constexpr size_t kQEncSlab = (size_t)kN*kN*kHD;  // 2304

__device__ __forceinline__ float wred_sum(float v){
  #pragma unroll
  for (int m=32;m>0;m>>=1) v += __shfl_xor(v, m, 64);
  return v;
}
__device__ __forceinline__ float wred_max(float v){
  #pragma unroll
  for (int m=32;m>0;m>>=1) v = fmaxf(v, __shfl_xor(v, m, 64));
  return v;
}

// ---------------------------------------------------------------------------
// Generic f32 GEMM: C[M,N] = concat(A1,A2)[M,K] @ W[K,N] + bias (+R) (relu?)
// A1 has leading dim K1, A2 (optional) leading dim K-K1.
// Tiles 64x64, BK=16, 256 threads, 4x4 per thread.
// ---------------------------------------------------------------------------
__global__ __launch_bounds__(256) void gemm_k(
    const float* __restrict__ A1, const float* __restrict__ A2, int K1,
    const float* __restrict__ W, const float* __restrict__ bias,
    const float* __restrict__ R, float* __restrict__ C,
    int M, int N, int K, int doRelu)
{
  __shared__ float As[16][65];   // [k][m], padded
  __shared__ float Ws[16][64];   // [k][n]
  const int tid = threadIdx.x;
  const int tx = tid & 15, ty = tid >> 4;
  const int row0 = blockIdx.y*64, col0 = blockIdx.x*64;
  const int ar = tid >> 2, ak = (tid & 3)*4;
  const int wr = tid >> 4, wc = (tid & 15)*4;
  const int K2 = K - K1;
  float acc[4][4] = {};
  for (int kt = 0; kt < K; kt += 16) {
    const int kk = kt + ak;
    const float* ap = (kk < K1) ? (A1 + (size_t)(row0+ar)*K1 + kk)
                                : (A2 + (size_t)(row0+ar)*K2 + (kk - K1));
    float4 av = *(const float4*)ap;
    As[ak+0][ar]=av.x; As[ak+1][ar]=av.y; As[ak+2][ar]=av.z; As[ak+3][ar]=av.w;
    float4 wv = *(const float4*)(W + (size_t)(kt+wr)*N + col0 + wc);
    *(float4*)(&Ws[wr][wc]) = wv;
    __syncthreads();
    #pragma unroll
    for (int k2=0;k2<16;++k2) {
      float a[4], b[4];
      #pragma unroll
      for (int i=0;i<4;++i) a[i]=As[k2][ty*4+i];
      #pragma unroll
      for (int j=0;j<4;++j) b[j]=Ws[k2][tx*4+j];
      #pragma unroll
      for (int i=0;i<4;++i)
        #pragma unroll
        for (int j=0;j<4;++j) acc[i][j] = fmaf(a[i], b[j], acc[i][j]);
    }
    __syncthreads();
  }
  #pragma unroll
  for (int i=0;i<4;++i){
    const int r = row0 + ty*4 + i;
    #pragma unroll
    for (int j=0;j<4;++j){
      const int cc = col0 + tx*4 + j;
      float v = acc[i][j] + bias[cc];
      if (R) v += R[(size_t)r*N + cc];
      if (doRelu) v = fmaxf(v, 0.f);
      C[(size_t)r*N + cc] = v;
    }
  }
}

// ---------------------------------------------------------------------------
// Self-attn prep: deinterleave qkv, apply RoPE to q,k.
// Q [g][i][c] roped, Kt [g][c][i] roped, V [g][i][c]; g=(b*N+n)*H+h
// ---------------------------------------------------------------------------
__global__ void prep_self_k(const float* __restrict__ qkv, const float* __restrict__ enc,
                            float* __restrict__ Q, float* __restrict__ Kt, float* __restrict__ V)
{
  const size_t idx = (size_t)blockIdx.x*256 + threadIdx.x; // g*512*64 + i*64 + c
  const int c  = idx & 63;
  const size_t gi = idx >> 6;
  const int i  = gi & 511;
  const int g  = (int)(gi >> 9);
  const int h  = g & 3;
  const int bn = g >> 2;
  const int n  = bn % kN;
  const float* base = qkv + ((size_t)bn*kM + i)*768 + h*192;
  const float q = base[c*3+0], k = base[c*3+1], v = base[c*3+2];
  const int cp = c ^ 1;
  const float qp = base[cp*3+0], kp = base[cp*3+1];
  const float sgn = (c & 1) ? 1.f : -1.f;
  const size_t eoff = ((size_t)(n*kM + i))*kHD + c;
  const float e0 = enc[eoff], e1 = enc[kEncSlab + eoff];
  Q[idx] = q*e0 + sgn*qp*e1;
  V[idx] = v;
  Kt[((size_t)g*kHD + c)*kM + i] = k*e0 + sgn*kp*e1;
}

// s2s prep: Q raw [g=(b*H+h)*N+j][p][c]; Kt roped by k_enc; V. (group=(b,h,view))
__global__ void prep_s2s_k(const float* __restrict__ qkv, const float* __restrict__ kenc,
                           float* __restrict__ Q, float* __restrict__ Kt, float* __restrict__ V)
{
  const size_t idx = (size_t)blockIdx.x*256 + threadIdx.x;
  const int c = idx & 63;
  const size_t gp = idx >> 6;
  const int p = gp & 511;
  const int g = (int)(gp >> 9);     // (b*4+h)*6 + view
  const int view = g % kN;
  const int bh = g / kN;
  const int h = bh & 3;
  const int b = bh >> 2;
  const float* base = qkv + ((size_t)(b*kN+view)*kM + p)*768 + h*192;
  const float q = base[c*3+0], k = base[c*3+1], v = base[c*3+2];
  const float kp = base[(c^1)*3+1];
  const float sgn = (c & 1) ? 1.f : -1.f;
  const size_t eoff = ((size_t)(view*kM + p))*kHD + c;
  const float e0 = kenc[eoff], e1 = kenc[kEncSlab + eoff];
  Q[idx] = q;
  V[idx] = v;
  Kt[((size_t)g*kHD + c)*kM + p] = k*e0 + sgn*kp*e1;
}

// cross prep: deinterleave kv buffer [rows][512] (h*128 + c*2 + {k,v})
__global__ void prep_cross_k(const float* __restrict__ kv,
                             float* __restrict__ Kt, float* __restrict__ V)
{
  const size_t idx = (size_t)blockIdx.x*256 + threadIdx.x;
  const int c = idx & 63;
  const size_t gi = idx >> 6;
  const int i = gi & 511;
  const int g = (int)(gi >> 9);
  const int h = g & 3;
  const int bn = g >> 2;
  const float* base = kv + ((size_t)bn*kM + i)*512 + h*128;
  V[idx] = base[c*2+1];
  Kt[((size_t)g*kHD + c)*kM + i] = base[c*2+0];
}

// ---------------------------------------------------------------------------
// Attention (512 keys), 4 waves/block, each wave owns 4 query rows.
// CROSSQ=0: Q pre-packed [g][qi][c]. CROSSQ=1: Q is linear out [row][h*64+c].
// ctx written [row][h*64+c].
// ---------------------------------------------------------------------------
template<int CROSSQ>
__global__ __launch_bounds__(256) void attn_k(const float* __restrict__ Q,
    const float* __restrict__ Kt, const float* __restrict__ V, float* __restrict__ ctx)
{
  __shared__ float q_s[4][4][64];
  __shared__ float p_s[4][4][512];
  const int w = threadIdx.x >> 6, lane = threadIdx.x & 63;
  const int g   = blockIdx.x >> 5;           // 32 tiles of 16 rows per group
  const int qi0 = (blockIdx.x & 31)*16 + w*4;
  const int h = g & 3, bn = g >> 2;
  #pragma unroll
  for (int r=0;r<4;++r){
    const int qi = qi0 + r;
    float qv = CROSSQ ? Q[((size_t)bn*kM + qi)*kD + h*kHD + lane]
                      : Q[((size_t)g*kM + qi)*kHD + lane];
    q_s[w][r][lane] = qv;
  }
  __syncthreads();
  float acc[4][8];
  #pragma unroll
  for (int r=0;r<4;++r)
    #pragma unroll
    for (int j=0;j<8;++j) acc[r][j]=0.f;
  const float* KtG = Kt + (size_t)g*kHD*kM;
  #pragma unroll 2
  for (int c=0;c<64;++c){
    float kt[8];
    #pragma unroll
    for (int j=0;j<8;++j) kt[j] = KtG[c*kM + lane + j*64];
    #pragma unroll
    for (int r=0;r<4;++r){
      const float qc = q_s[w][r][c];
      #pragma unroll
      for (int j=0;j<8;++j) acc[r][j] = fmaf(qc, kt[j], acc[r][j]);
    }
  }
  float inv[4];
  #pragma unroll
  for (int r=0;r<4;++r){
    float mx = -1e30f;
    #pragma unroll
    for (int j=0;j<8;++j){ acc[r][j] *= 0.125f; mx = fmaxf(mx, acc[r][j]); }
    mx = wred_max(mx);
    float s = 0.f;
    #pragma unroll
    for (int j=0;j<8;++j){ float p = expf(acc[r][j]-mx); p_s[w][r][lane+j*64]=p; s+=p; }
    inv[r] = 1.f / wred_sum(s);
  }
  __syncthreads();
  const float* VG = V + (size_t)g*kM*kHD;
  float o[4] = {0.f,0.f,0.f,0.f};
  #pragma unroll 4
  for (int k=0;k<512;++k){
    const float vv = VG[k*kHD + lane];
    #pragma unroll
    for (int r=0;r<4;++r) o[r] = fmaf(p_s[w][r][k], vv, o[r]);
  }
  #pragma unroll
  for (int r=0;r<4;++r)
    ctx[((size_t)bn*kM + qi0 + r)*kD + h*kHD + lane] = o[r]*inv[r];
}

// ---------------------------------------------------------------------------
// s2s attention: wave per (b,h,col, 4 p-rows). For each of 5 off-diagonal
// (i,j) pairs of output column `col`: rope q (view j) with q_enc[i,j], attend
// into view i, accumulate mean/5. Deterministic, no atomics.
// ---------------------------------------------------------------------------
__global__ __launch_bounds__(256) void attn_s2s_k(const float* __restrict__ Qraw,
    const float* __restrict__ Kt, const float* __restrict__ V,
    const float* __restrict__ qenc, float* __restrict__ ctx)
{
  __shared__ float q_s[4][4][64];
  __shared__ float p_s[4][4][512];
  const int w = threadIdx.x >> 6, lane = threadIdx.x & 63;
  const int wave = blockIdx.x*4 + w;
  const int pc  = wave & 127;          // p chunk (×4)
  const int cb  = wave >> 7;
  const int col = cb % kN;
  const int bh  = cb / kN;             // b*4+h
  const int p0  = pc*4;
  float o[4] = {0.f,0.f,0.f,0.f};
  const float sgn = (lane & 1) ? 1.f : -1.f;
  for (int r5 = 0; r5 < 5; ++r5){
    const int e  = r5*6 + col;
    const int iv = e/5;
    const int j0 = e%5;
    const int jv = j0 + (j0 >= iv ? 1 : 0);
    const size_t qe = (size_t)(iv*kN + jv)*kHD + lane;
    const float e0 = qenc[qe], e1 = qenc[kQEncSlab + qe];
    #pragma unroll
    for (int r=0;r<4;++r){
      const float* qb = Qraw + ((size_t)(bh*kN + jv)*kM + (p0+r))*kHD;
      q_s[w][r][lane] = qb[lane]*e0 + sgn*qb[lane^1]*e1;
    }
    __syncthreads();
    float acc[4][8];
    #pragma unroll
    for (int r=0;r<4;++r)
      #pragma unroll
      for (int j=0;j<8;++j) acc[r][j]=0.f;
    const float* KtG = Kt + (size_t)(bh*kN+iv)*kHD*kM;
    #pragma unroll 2
    for (int c=0;c<64;++c){
      float kt[8];
      #pragma unroll
      for (int j=0;j<8;++j) kt[j] = KtG[c*kM + lane + j*64];
      #pragma unroll
      for (int r=0;r<4;++r){
        const float qc = q_s[w][r][c];
        #pragma unroll
        for (int j=0;j<8;++j) acc[r][j] = fmaf(qc, kt[j], acc[r][j]);
      }
    }
    float inv[4];
    #pragma unroll
    for (int r=0;r<4;++r){
      float mx = -1e30f;
      #pragma unroll
      for (int j=0;j<8;++j){ acc[r][j] *= 0.125f; mx = fmaxf(mx, acc[r][j]); }
      mx = wred_max(mx);
      float s = 0.f;
      #pragma unroll
      for (int j=0;j<8;++j){ float p = expf(acc[r][j]-mx); p_s[w][r][lane+j*64]=p; s+=p; }
      inv[r] = 0.2f / wred_sum(s);   // fold mean(1/5)
    }
    __syncthreads();
    const float* VG = V + (size_t)(bh*kN+iv)*kM*kHD;
    float t[4] = {0.f,0.f,0.f,0.f};
    #pragma unroll 4
    for (int k=0;k<512;++k){
      const float vv = VG[k*kHD + lane];
      #pragma unroll
      for (int r=0;r<4;++r) t[r] = fmaf(p_s[w][r][k], vv, t[r]);
    }
    #pragma unroll
    for (int r=0;r<4;++r) o[r] += t[r]*inv[r];
    __syncthreads();
  }
  const int b = bh >> 2, h = bh & 3;
  #pragma unroll
  for (int r=0;r<4;++r)
    ctx[((size_t)(b*kN+col)*kM + (p0+r))*kD + h*kHD + lane] = o[r];
}

// ---------------------------------------------------------------------------
// t2t attention: tiny sequence (N=6). One thread per (b,h,nq,mpos).
// Reads straight from the interleaved qkv buffer; ctx [row][h*64+c].
// ---------------------------------------------------------------------------
__global__ void attn_t2t_k(const float* __restrict__ qkv, float* __restrict__ ctx)
{
  const int idx = blockIdx.x*256 + threadIdx.x;     // 24576 threads
  const int mpos = idx & 511;
  int t = idx >> 9;
  const int nq = t % kN;
  const int bh = t / kN;
  const int h = bh & 3, b = bh >> 2;
  const float* kb[kN];
  #pragma unroll
  for (int nk=0;nk<kN;++nk)
    kb[nk] = qkv + ((size_t)(b*kN+nk)*kM + mpos)*768 + h*192;
  const float* qb = kb[nq];
  float sim[kN] = {0,0,0,0,0,0};
  for (int c=0;c<64;++c){
    const float qc = qb[c*3+0];
    #pragma unroll
    for (int nk=0;nk<kN;++nk) sim[nk] = fmaf(qc, kb[nk][c*3+1], sim[nk]);
  }
  float mx = -1e30f;
  #pragma unroll
  for (int nk=0;nk<kN;++nk){ sim[nk] *= 0.125f; mx = fmaxf(mx, sim[nk]); }
  float p[kN], s = 0.f;
  #pragma unroll
  for (int nk=0;nk<kN;++nk){ p[nk] = expf(sim[nk]-mx); s += p[nk]; }
  const float invs = 1.f/s;
  float* outp = ctx + ((size_t)(b*kN+nq)*kM + mpos)*kD + h*kHD;
  for (int c=0;c<64;++c){
    float ov = 0.f;
    #pragma unroll
    for (int nk=0;nk<kN;++nk) ov = fmaf(p[nk], kb[nk][c*3+2], ov);
    outp[c] = ov*invs;
  }
}

// LayerNorm(512) + exact GELU, in place. One block per row.
__global__ __launch_bounds__(256) void lngelu_k(float* __restrict__ hbuf,
    const float* __restrict__ g, const float* __restrict__ b)
{
  const int row = blockIdx.x;
  const int tid = threadIdx.x;
  float* x = hbuf + (size_t)row*512;
  const float v0 = x[tid], v1 = x[tid+256];
  const int w = tid >> 6, lane = tid & 63;
  __shared__ float red[2][4];
  const float s1 = wred_sum(v0+v1);
  const float s2 = wred_sum(v0*v0+v1*v1);
  if (lane == 0){ red[0][w]=s1; red[1][w]=s2; }
  __syncthreads();
  const float mean = (red[0][0]+red[0][1]+red[0][2]+red[0][3]) * (1.f/512.f);
  const float ms   = (red[1][0]+red[1][1]+red[1][2]+red[1][3]) * (1.f/512.f);
  const float rs = rsqrtf(ms - mean*mean + 1e-5f);
  const float y0 = (v0-mean)*rs*g[tid]     + b[tid];
  const float y1 = (v1-mean)*rs*g[tid+256] + b[tid+256];
  x[tid]     = 0.5f*y0*(1.f+erff(y0*0.70710678118654752f));
  x[tid+256] = 0.5f*y1*(1.f+erff(y1*0.70710678118654752f));
}

// conf final dot: out[row] = tmp[row,:] . w2 + b2. Wave per row.
__global__ void conf_dot_k(const float* __restrict__ tmp, const float* __restrict__ w2,
                           const float* __restrict__ b2, float* __restrict__ out)
{
  const int w = threadIdx.x >> 6, lane = threadIdx.x & 63;
  const int row = blockIdx.x*4 + w;
  const float* t = tmp + (size_t)row*kD;
  float s = 0.f;
  #pragma unroll
  for (int j=0;j<4;++j) s = fmaf(t[lane+j*64], w2[lane+j*64], s);
  s = wred_sum(s);
  if (lane == 0) out[row] = s + b2[0];
}

// ---------------------------------------------------------------------------
static inline void gemm(hipStream_t st, const float* A1, const float* A2, int K1,
                        const float* W, const float* bias, const float* R, float* C,
                        int M, int N, int K, int relu)
{
  dim3 grid(N/64, M/64);
  gemm_k<<<grid, 256, 0, st>>>(A1, A2, K1, W, bias, R, C, M, N, K, relu);
}

extern "C" void kernel_launch(void* const* d_in, const int* in_sizes, int n_in,
                              void* d_out, int out_size, void* d_ws, size_t ws_size,
                              hipStream_t stream)
{
  auto F = [&](int i){ return (const float*)d_in[i]; };
  const float* t_desc = F(0);
  const float* s_desc = F(1);
  const float* t_enc  = F(2);
  const float* s_enc  = F(3);
  const float* q_enc  = F(4);
  const float* k_enc  = F(5);
  // weight bases: sa=6, ss=16, tt=26, ca=36, cf=48
  // per block: +0 qkv_w +1 qkv_b +2 out_w +3 out_b +4 f1_w +5 f1_b +6 ln_g +7 ln_b +8 f2_w +9 f2_b

  float* ws = (float*)d_ws;
  const size_t TOK = (size_t)kRows*kD;      // 1,572,864
  float* xt   = ws;
  float* xs   = ws + TOK;
  float* qkvb = ws + 2*TOK;                 // 3*TOK floats
  float* Ktb  = ws + 5*TOK;
  float* Vb   = ws + 6*TOK;
  float* Qb   = ws + 7*TOK;
  float* ctxb = ws + 8*TOK;
  float* msgb = ws + 9*TOK;
  float* hbuf = ws + 10*TOK;                // 2*TOK floats
  float* kvb  = qkvb + TOK;                 // cross kv region inside qkvb

  float* out_t2   = (float*)d_out;
  float* out_s2   = out_t2 + TOK;
  float* out_conf = out_t2 + 2*TOK;

  const int PREP_BLOCKS = (kGrp*kM*kHD)/256;   // 6144
  const int ATTN_BLOCKS = (kGrp*kM)/16;        // 1536

  // full self/t2t/s2s share this FFN tail
  auto ffn_tail = [&](const float* xin, int wb, float* xout){
    gemm(stream, xin, msgb, kD, F(wb+4), F(wb+5), nullptr, hbuf, kRows, 2*kD, 2*kD, 0);
    lngelu_k<<<kRows, 256, 0, stream>>>(hbuf, F(wb+6), F(wb+7));
    gemm(stream, hbuf, nullptr, 2*kD, F(wb+8), F(wb+9), xin, xout, kRows, kD, 2*kD, 0);
  };

  auto self_block = [&](const float* xin, const float* enc, int wb, float* xout){
    gemm(stream, xin, nullptr, kD, F(wb+0), F(wb+1), nullptr, qkvb, kRows, 3*kD, kD, 0);
    prep_self_k<<<PREP_BLOCKS, 256, 0, stream>>>(qkvb, enc, Qb, Ktb, Vb);
    attn_k<0><<<ATTN_BLOCKS, 256, 0, stream>>>(Qb, Ktb, Vb, ctxb);
    gemm(stream, ctxb, nullptr, kD, F(wb+2), F(wb+3), nullptr, msgb, kRows, kD, kD, 0);
    ffn_tail(xin, wb, xout);
  };

  // 1) SelfBlock on t and s (shared sa weights)
  self_block(t_desc, t_enc, 6, xt);
  self_block(s_desc, s_enc, 6, xs);

  // 2) t2t block (tt weights), in place on xt
  {
    const int wb = 26;
    gemm(stream, xt, nullptr, kD, F(wb+0), F(wb+1), nullptr, qkvb, kRows, 3*kD, kD, 0);
    attn_t2t_k<<<(kB*kH*kN*kM)/256, 256, 0, stream>>>(qkvb, ctxb);
    gemm(stream, ctxb, nullptr, kD, F(wb+2), F(wb+3), nullptr, msgb, kRows, kD, kD, 0);
    ffn_tail(xt, wb, xt);
  }

  // 3) s2s block (ss weights), in place on xs
  {
    const int wb = 16;
    gemm(stream, xs, nullptr, kD, F(wb+0), F(wb+1), nullptr, qkvb, kRows, 3*kD, kD, 0);
    prep_s2s_k<<<PREP_BLOCKS, 256, 0, stream>>>(qkvb, k_enc, Qb, Ktb, Vb);
    attn_s2s_k<<<ATTN_BLOCKS, 256, 0, stream>>>(Qb, Ktb, Vb, q_enc, ctxb);
    gemm(stream, ctxb, nullptr, kD, F(wb+2), F(wb+3), nullptr, msgb, kRows, kD, kD, 0);
    ffn_tail(xs, wb, xs);
  }

  // 4) confidence head from xs (post-s2s)
  gemm(stream, xs, nullptr, kD, F(48), F(49), nullptr, msgb, kRows, kD, kD, 1);
  conf_dot_k<<<kRows/4, 256, 0, stream>>>(msgb, F(50), F(51), out_conf);

  // 5) cross blocks (shared ca weights)
  auto cross_block = [&](const float* d0, const float* d1, float* outp){
    gemm(stream, d0, nullptr, kD, F(36), F(37), nullptr, qkvb, kRows, kD, kD, 0);   // q
    gemm(stream, d1, nullptr, kD, F(38), F(39), nullptr, kvb,  kRows, 2*kD, kD, 0); // kv
    prep_cross_k<<<PREP_BLOCKS, 256, 0, stream>>>(kvb, Ktb, Vb);
    attn_k<1><<<ATTN_BLOCKS, 256, 0, stream>>>(qkvb, Ktb, Vb, ctxb);
    gemm(stream, ctxb, nullptr, kD, F(40), F(41), nullptr, msgb, kRows, kD, kD, 0);
    gemm(stream, d0, msgb, kD, F(42), F(43), nullptr, hbuf, kRows, 2*kD, 2*kD, 0);
    lngelu_k<<<kRows, 256, 0, stream>>>(hbuf, F(44), F(45));
    gemm(stream, hbuf, nullptr, 2*kD, F(46), F(47), d0, outp, kRows, kD, 2*kD, 0);
  };
  cross_block(xt, xs, out_t2);
  cross_block(xs, xt, out_s2);
}

// Round 2
// 1391.938 us; speedup vs baseline: 1.5330x; 1.5330x over previous
//
#include <hip/hip_runtime.h>
#include <math.h>

// Problem constants
constexpr int kD   = 256;   // model dim
constexpr int kH   = 4;     // heads
constexpr int kHD  = 64;    // head dim
constexpr int kB   = 2;
constexpr int kN   = 6;     // views
constexpr int kM   = 512;   // keypoints (M == NS)
constexpr int kRows = kB*kN*kM;        // 6144 token rows
constexpr int kGrp  = kB*kN*kH;        // 48 attention groups
constexpr size_t kEncSlab = (size_t)kN*kM*kHD;   // 196608
constexpr size_t kQEncSlab = (size_t)kN*kN*kHD;  // 2304

typedef unsigned short u16;
typedef __attribute__((ext_vector_type(8))) short s16x8;
typedef __attribute__((ext_vector_type(4))) float f32x4;

__device__ __forceinline__ float wred_sum(float v){
  #pragma unroll
  for (int m=32;m>0;m>>=1) v += __shfl_xor(v, m, 64);
  return v;
}
__device__ __forceinline__ float wred_max(float v){
  #pragma unroll
  for (int m=32;m>0;m>>=1) v = fmaxf(v, __shfl_xor(v, m, 64));
  return v;
}
__device__ __forceinline__ u16 f2b(float x){
  union { float f; unsigned u; } a; a.f = x;
  unsigned r = a.u + 0x7fffu + ((a.u >> 16) & 1u);
  return (u16)(r >> 16);
}

// ---------------------------------------------------------------------------
// Weight transpose+cast: W[K][N] f32 -> Wt[N][K] bf16. Batched over matrices.
// ---------------------------------------------------------------------------
struct WtDesc { const float* W; u16* Wt; int K; int N; int ntiles; };
struct WtTable { WtDesc d[18]; };

__global__ __launch_bounds__(256) void wtcast_k(WtTable tab)
{
  int t = blockIdx.x, mi = 0;
  while (t >= tab.d[mi].ntiles) { t -= tab.d[mi].ntiles; ++mi; }
  const float* W = tab.d[mi].W;
  u16* Wt = tab.d[mi].Wt;
  const int K = tab.d[mi].K, N = tab.d[mi].N;
  const int ntn = N >> 5;
  const int n0 = (t % ntn) * 32, k0 = (t / ntn) * 32;
  __shared__ float tile[32][33];
  const int tx = threadIdx.x & 31, ty = threadIdx.x >> 5;   // 32 x 8
  #pragma unroll
  for (int i = 0; i < 32; i += 8)
    tile[ty+i][tx] = W[(size_t)(k0+ty+i)*N + n0+tx];
  __syncthreads();
  #pragma unroll
  for (int i = 0; i < 32; i += 8)
    Wt[(size_t)(n0+ty+i)*K + k0+tx] = f2b(tile[tx][ty+i]);
}

// ---------------------------------------------------------------------------
// bf16 MFMA GEMM: C[M,N] f32 = concat(A1,A2)[M,K] f32 @ W (as Wt[N][K] bf16)
//                 + bias (+R) (relu?)
// 128x128 tile, BK=32, 4 waves (2x2 of 64x64), mfma_f32_16x16x32_bf16.
// LDS tiles XOR-swizzled (granule ^= (row>>1)&3) for conflict-free b128 reads.
// ---------------------------------------------------------------------------
__global__ __launch_bounds__(256) void mmad_k(
    const float* __restrict__ A1, const float* __restrict__ A2, int K1,
    const u16* __restrict__ Wt, const float* __restrict__ bias,
    const float* __restrict__ R, float* __restrict__ C,
    int M, int N, int K, int doRelu)
{
  __shared__ u16 As[128*32];   // [row][k] bf16, swizzled; 8 KB
  __shared__ u16 Bs[128*32];   // [col][k] bf16, swizzled; 8 KB
  const int tid = threadIdx.x;
  const int lane = tid & 63, w = tid >> 6;
  const int row0 = blockIdx.y*128, col0 = blockIdx.x*128;
  const int wr = (w >> 1)*64, wc = (w & 1)*64;
  const int ar = tid >> 1;         // staging row 0..127
  const int ah = tid & 1;          // k-half (16 elems)
  const int K2 = K - K1;
  f32x4 acc[4][4] = {};

  for (int kt = 0; kt < K; kt += 32) {
    // ---- stage A (f32 -> bf16) ----
    {
      const int kk = kt + ah*16;
      const float* ap = (kk < K1) ? A1 + (size_t)(row0+ar)*K1 + kk
                                  : A2 + (size_t)(row0+ar)*K2 + (kk - K1);
      union { u16 u[16]; s16x8 v[2]; } tmp;
      #pragma unroll
      for (int i = 0; i < 16; i += 4) {
        f32x4 v4 = *(const f32x4*)(ap + i);
        tmp.u[i+0] = f2b(v4.x); tmp.u[i+1] = f2b(v4.y);
        tmp.u[i+2] = f2b(v4.z); tmp.u[i+3] = f2b(v4.w);
      }
      const int sw = (ar >> 1) & 3;
      *(s16x8*)(&As[ar*32 + (((ah*2+0)^sw))*8]) = tmp.v[0];
      *(s16x8*)(&As[ar*32 + (((ah*2+1)^sw))*8]) = tmp.v[1];
    }
    // ---- stage B (bf16 copy) ----
    {
      const u16* bp = Wt + (size_t)(col0+ar)*K + kt + ah*16;
      s16x8 b0 = *(const s16x8*)(bp);
      s16x8 b1 = *(const s16x8*)(bp + 8);
      const int sw = (ar >> 1) & 3;
      *(s16x8*)(&Bs[ar*32 + (((ah*2+0)^sw))*8]) = b0;
      *(s16x8*)(&Bs[ar*32 + (((ah*2+1)^sw))*8]) = b1;
    }
    __syncthreads();
    // ---- compute: 4 A frags x 4 B frags, 16 MFMA ----
    s16x8 af[4], bfv[4];
    #pragma unroll
    for (int fm = 0; fm < 4; ++fm) {
      const int r = wr + fm*16 + (lane & 15);
      const int g = (lane >> 4) ^ ((r >> 1) & 3);
      af[fm] = *(const s16x8*)(&As[r*32 + g*8]);
    }
    #pragma unroll
    for (int fn = 0; fn < 4; ++fn) {
      const int c = wc + fn*16 + (lane & 15);
      const int g = (lane >> 4) ^ ((c >> 1) & 3);
      bfv[fn] = *(const s16x8*)(&Bs[c*32 + g*8]);
    }
    #pragma unroll
    for (int fm = 0; fm < 4; ++fm)
      #pragma unroll
      for (int fn = 0; fn < 4; ++fn)
        acc[fm][fn] = __builtin_amdgcn_mfma_f32_16x16x32_bf16(af[fm], bfv[fn], acc[fm][fn], 0, 0, 0);
    __syncthreads();
  }

  // ---- epilogue: C/D layout col=lane&15, row=(lane>>4)*4+j ----
  #pragma unroll
  for (int fm = 0; fm < 4; ++fm) {
    const int rbase = row0 + wr + fm*16 + (lane >> 4)*4;
    #pragma unroll
    for (int fn = 0; fn < 4; ++fn) {
      const int cc = col0 + wc + fn*16 + (lane & 15);
      const float bv = bias[cc];
      #pragma unroll
      for (int j = 0; j < 4; ++j) {
        const size_t idx = (size_t)(rbase + j)*N + cc;
        float v = acc[fm][fn][j] + bv;
        if (R) v += R[idx];
        if (doRelu) v = fmaxf(v, 0.f);
        C[idx] = v;
      }
    }
  }
}

// ---------------------------------------------------------------------------
// Self-attn prep: deinterleave qkv, apply RoPE to q,k.
// ---------------------------------------------------------------------------
__global__ void prep_self_k(const float* __restrict__ qkv, const float* __restrict__ enc,
                            float* __restrict__ Q, float* __restrict__ Kt, float* __restrict__ V)
{
  const size_t idx = (size_t)blockIdx.x*256 + threadIdx.x;
  const int c  = idx & 63;
  const size_t gi = idx >> 6;
  const int i  = gi & 511;
  const int g  = (int)(gi >> 9);
  const int h  = g & 3;
  const int bn = g >> 2;
  const int n  = bn % kN;
  const float* base = qkv + ((size_t)bn*kM + i)*768 + h*192;
  const float q = base[c*3+0], k = base[c*3+1], v = base[c*3+2];
  const int cp = c ^ 1;
  const float qp = base[cp*3+0], kp = base[cp*3+1];
  const float sgn = (c & 1) ? 1.f : -1.f;
  const size_t eoff = ((size_t)(n*kM + i))*kHD + c;
  const float e0 = enc[eoff], e1 = enc[kEncSlab + eoff];
  Q[idx] = q*e0 + sgn*qp*e1;
  V[idx] = v;
  Kt[((size_t)g*kHD + c)*kM + i] = k*e0 + sgn*kp*e1;
}

__global__ void prep_s2s_k(const float* __restrict__ qkv, const float* __restrict__ kenc,
                           float* __restrict__ Q, float* __restrict__ Kt, float* __restrict__ V)
{
  const size_t idx = (size_t)blockIdx.x*256 + threadIdx.x;
  const int c = idx & 63;
  const size_t gp = idx >> 6;
  const int p = gp & 511;
  const int g = (int)(gp >> 9);     // (b*4+h)*6 + view
  const int view = g % kN;
  const int bh = g / kN;
  const int h = bh & 3;
  const int b = bh >> 2;
  const float* base = qkv + ((size_t)(b*kN+view)*kM + p)*768 + h*192;
  const float q = base[c*3+0], k = base[c*3+1], v = base[c*3+2];
  const float kp = base[(c^1)*3+1];
  const float sgn = (c & 1) ? 1.f : -1.f;
  const size_t eoff = ((size_t)(view*kM + p))*kHD + c;
  const float e0 = kenc[eoff], e1 = kenc[kEncSlab + eoff];
  Q[idx] = q;
  V[idx] = v;
  Kt[((size_t)g*kHD + c)*kM + p] = k*e0 + sgn*kp*e1;
}

__global__ void prep_cross_k(const float* __restrict__ kv,
                             float* __restrict__ Kt, float* __restrict__ V)
{
  const size_t idx = (size_t)blockIdx.x*256 + threadIdx.x;
  const int c = idx & 63;
  const size_t gi = idx >> 6;
  const int i = gi & 511;
  const int g = (int)(gi >> 9);
  const int h = g & 3;
  const int bn = g >> 2;
  const float* base = kv + ((size_t)bn*kM + i)*512 + h*128;
  V[idx] = base[c*2+1];
  Kt[((size_t)g*kHD + c)*kM + i] = base[c*2+0];
}

// ---------------------------------------------------------------------------
// Attention (512 keys), 4 waves/block, each wave owns 4 query rows.
// XCD-bijective block swizzle: 1536 blocks = 8 chunks of 192 (6 groups) so all
// 32 blocks of a group share one XCD's L2 slab.
// ---------------------------------------------------------------------------
template<int CROSSQ>
__global__ __launch_bounds__(256) void attn_k(const float* __restrict__ Q,
    const float* __restrict__ Kt, const float* __restrict__ V, float* __restrict__ ctx)
{
  __shared__ float q_s[4][4][64];
  __shared__ float p_s[4][4][512];
  const int w = threadIdx.x >> 6, lane = threadIdx.x & 63;
  const int bij = ((blockIdx.x & 7) * 192) + (blockIdx.x >> 3);
  const int g   = bij >> 5;
  const int qi0 = (bij & 31)*16 + w*4;
  const int h = g & 3, bn = g >> 2;
  #pragma unroll
  for (int r=0;r<4;++r){
    const int qi = qi0 + r;
    float qv = CROSSQ ? Q[((size_t)bn*kM + qi)*kD + h*kHD + lane]
                      : Q[((size_t)g*kM + qi)*kHD + lane];
    q_s[w][r][lane] = qv;
  }
  __syncthreads();
  float acc[4][8];
  #pragma unroll
  for (int r=0;r<4;++r)
    #pragma unroll
    for (int j=0;j<8;++j) acc[r][j]=0.f;
  const float* KtG = Kt + (size_t)g*kHD*kM;
  #pragma unroll 2
  for (int c=0;c<64;++c){
    float kt[8];
    #pragma unroll
    for (int j=0;j<8;++j) kt[j] = KtG[c*kM + lane + j*64];
    #pragma unroll
    for (int r=0;r<4;++r){
      const float qc = q_s[w][r][c];
      #pragma unroll
      for (int j=0;j<8;++j) acc[r][j] = fmaf(qc, kt[j], acc[r][j]);
    }
  }
  float inv[4];
  #pragma unroll
  for (int r=0;r<4;++r){
    float mx = -1e30f;
    #pragma unroll
    for (int j=0;j<8;++j){ acc[r][j] *= 0.125f; mx = fmaxf(mx, acc[r][j]); }
    mx = wred_max(mx);
    float s = 0.f;
    #pragma unroll
    for (int j=0;j<8;++j){ float p = expf(acc[r][j]-mx); p_s[w][r][lane+j*64]=p; s+=p; }
    inv[r] = 1.f / wred_sum(s);
  }
  __syncthreads();
  const float* VG = V + (size_t)g*kM*kHD;
  float o[4] = {0.f,0.f,0.f,0.f};
  #pragma unroll 8
  for (int k=0;k<512;++k){
    const float vv = VG[k*kHD + lane];
    #pragma unroll
    for (int r=0;r<4;++r) o[r] = fmaf(p_s[w][r][k], vv, o[r]);
  }
  #pragma unroll
  for (int r=0;r<4;++r)
    ctx[((size_t)bn*kM + qi0 + r)*kD + h*kHD + lane] = o[r]*inv[r];
}

// ---------------------------------------------------------------------------
// s2s attention with the same XCD swizzle (chunk r == bh r: 1.5 MB slab in L2).
// ---------------------------------------------------------------------------
__global__ __launch_bounds__(256) void attn_s2s_k(const float* __restrict__ Qraw,
    const float* __restrict__ Kt, const float* __restrict__ V,
    const float* __restrict__ qenc, float* __restrict__ ctx)
{
  __shared__ float q_s[4][4][64];
  __shared__ float p_s[4][4][512];
  const int w = threadIdx.x >> 6, lane = threadIdx.x & 63;
  const int bij = ((blockIdx.x & 7) * 192) + (blockIdx.x >> 3);
  const int wave = bij*4 + w;
  const int pc  = wave & 127;
  const int cb  = wave >> 7;
  const int col = cb % kN;
  const int bh  = cb / kN;
  const int p0  = pc*4;
  float o[4] = {0.f,0.f,0.f,0.f};
  const float sgn = (lane & 1) ? 1.f : -1.f;
  for (int r5 = 0; r5 < 5; ++r5){
    const int e  = r5*6 + col;
    const int iv = e/5;
    const int j0 = e%5;
    const int jv = j0 + (j0 >= iv ? 1 : 0);
    const size_t qe = (size_t)(iv*kN + jv)*kHD + lane;
    const float e0 = qenc[qe], e1 = qenc[kQEncSlab + qe];
    #pragma unroll
    for (int r=0;r<4;++r){
      const float* qb = Qraw + ((size_t)(bh*kN + jv)*kM + (p0+r))*kHD;
      q_s[w][r][lane] = qb[lane]*e0 + sgn*qb[lane^1]*e1;
    }
    __syncthreads();
    float acc[4][8];
    #pragma unroll
    for (int r=0;r<4;++r)
      #pragma unroll
      for (int j=0;j<8;++j) acc[r][j]=0.f;
    const float* KtG = Kt + (size_t)(bh*kN+iv)*kHD*kM;
    #pragma unroll 2
    for (int c=0;c<64;++c){
      float kt[8];
      #pragma unroll
      for (int j=0;j<8;++j) kt[j] = KtG[c*kM + lane + j*64];
      #pragma unroll
      for (int r=0;r<4;++r){
        const float qc = q_s[w][r][c];
        #pragma unroll
        for (int j=0;j<8;++j) acc[r][j] = fmaf(qc, kt[j], acc[r][j]);
      }
    }
    float inv[4];
    #pragma unroll
    for (int r=0;r<4;++r){
      float mx = -1e30f;
      #pragma unroll
      for (int j=0;j<8;++j){ acc[r][j] *= 0.125f; mx = fmaxf(mx, acc[r][j]); }
      mx = wred_max(mx);
      float s = 0.f;
      #pragma unroll
      for (int j=0;j<8;++j){ float p = expf(acc[r][j]-mx); p_s[w][r][lane+j*64]=p; s+=p; }
      inv[r] = 0.2f / wred_sum(s);
    }
    __syncthreads();
    const float* VG = V + (size_t)(bh*kN+iv)*kM*kHD;
    float t[4] = {0.f,0.f,0.f,0.f};
    #pragma unroll 8
    for (int k=0;k<512;++k){
      const float vv = VG[k*kHD + lane];
      #pragma unroll
      for (int r=0;r<4;++r) t[r] = fmaf(p_s[w][r][k], vv, t[r]);
    }
    #pragma unroll
    for (int r=0;r<4;++r) o[r] += t[r]*inv[r];
    __syncthreads();
  }
  const int b = bh >> 2, h = bh & 3;
  #pragma unroll
  for (int r=0;r<4;++r)
    ctx[((size_t)(b*kN+col)*kM + (p0+r))*kD + h*kHD + lane] = o[r];
}

// t2t attention: tiny sequence (N=6). One thread per (b,h,nq,mpos).
__global__ void attn_t2t_k(const float* __restrict__ qkv, float* __restrict__ ctx)
{
  const int idx = blockIdx.x*256 + threadIdx.x;
  const int mpos = idx & 511;
  int t = idx >> 9;
  const int nq = t % kN;
  const int bh = t / kN;
  const int h = bh & 3, b = bh >> 2;
  const float* kb[kN];
  #pragma unroll
  for (int nk=0;nk<kN;++nk)
    kb[nk] = qkv + ((size_t)(b*kN+nk)*kM + mpos)*768 + h*192;
  const float* qb = kb[nq];
  float sim[kN] = {0,0,0,0,0,0};
  for (int c=0;c<64;++c){
    const float qc = qb[c*3+0];
    #pragma unroll
    for (int nk=0;nk<kN;++nk) sim[nk] = fmaf(qc, kb[nk][c*3+1], sim[nk]);
  }
  float mx = -1e30f;
  #pragma unroll
  for (int nk=0;nk<kN;++nk){ sim[nk] *= 0.125f; mx = fmaxf(mx, sim[nk]); }
  float p[kN], s = 0.f;
  #pragma unroll
  for (int nk=0;nk<kN;++nk){ p[nk] = expf(sim[nk]-mx); s += p[nk]; }
  const float invs = 1.f/s;
  float* outp = ctx + ((size_t)(b*kN+nq)*kM + mpos)*kD + h*kHD;
  for (int c=0;c<64;++c){
    float ov = 0.f;
    #pragma unroll
    for (int nk=0;nk<kN;++nk) ov = fmaf(p[nk], kb[nk][c*3+2], ov);
    outp[c] = ov*invs;
  }
}

// LayerNorm(512) + exact GELU, in place. One block per row.
__global__ __launch_bounds__(256) void lngelu_k(float* __restrict__ hbuf,
    const float* __restrict__ g, const float* __restrict__ b)
{
  const int row = blockIdx.x;
  const int tid = threadIdx.x;
  float* x = hbuf + (size_t)row*512;
  const float v0 = x[tid], v1 = x[tid+256];
  const int w = tid >> 6, lane = tid & 63;
  __shared__ float red[2][4];
  const float s1 = wred_sum(v0+v1);
  const float s2 = wred_sum(v0*v0+v1*v1);
  if (lane == 0){ red[0][w]=s1; red[1][w]=s2; }
  __syncthreads();
  const float mean = (red[0][0]+red[0][1]+red[0][2]+red[0][3]) * (1.f/512.f);
  const float ms   = (red[1][0]+red[1][1]+red[1][2]+red[1][3]) * (1.f/512.f);
  const float rs = rsqrtf(ms - mean*mean + 1e-5f);
  const float y0 = (v0-mean)*rs*g[tid]     + b[tid];
  const float y1 = (v1-mean)*rs*g[tid+256] + b[tid+256];
  x[tid]     = 0.5f*y0*(1.f+erff(y0*0.70710678118654752f));
  x[tid+256] = 0.5f*y1*(1.f+erff(y1*0.70710678118654752f));
}

__global__ void conf_dot_k(const float* __restrict__ tmp, const float* __restrict__ w2,
                           const float* __restrict__ b2, float* __restrict__ out)
{
  const int w = threadIdx.x >> 6, lane = threadIdx.x & 63;
  const int row = blockIdx.x*4 + w;
  const float* t = tmp + (size_t)row*kD;
  float s = 0.f;
  #pragma unroll
  for (int j=0;j<4;++j) s = fmaf(t[lane+j*64], w2[lane+j*64], s);
  s = wred_sum(s);
  if (lane == 0) out[row] = s + b2[0];
}

// ---------------------------------------------------------------------------
extern "C" void kernel_launch(void* const* d_in, const int* in_sizes, int n_in,
                              void* d_out, int out_size, void* d_ws, size_t ws_size,
                              hipStream_t stream)
{
  auto F = [&](int i){ return (const float*)d_in[i]; };
  const float* t_desc = F(0);
  const float* s_desc = F(1);
  const float* t_enc  = F(2);
  const float* s_enc  = F(3);
  const float* q_enc  = F(4);
  const float* k_enc  = F(5);

  float* ws = (float*)d_ws;
  const size_t TOK = (size_t)kRows*kD;      // 1,572,864
  float* xt   = ws;
  float* xs   = ws + TOK;
  float* qkvb = ws + 2*TOK;                 // 3*TOK floats
  float* Ktb  = ws + 5*TOK;
  float* Vb   = ws + 6*TOK;
  float* Qb   = ws + 7*TOK;
  float* ctxb = ws + 8*TOK;
  float* msgb = ws + 9*TOK;
  float* hbuf = ws + 10*TOK;                // 2*TOK floats
  float* kvb  = qkvb + TOK;
  u16*   wsW  = (u16*)(ws + 12*TOK);        // bf16 transposed weights (~5.4 MB)

  float* out_t2   = (float*)d_out;
  float* out_s2   = out_t2 + TOK;
  float* out_conf = out_t2 + 2*TOK;

  // ---- weight transpose+cast table (once per call) ----
  WtTable tab;
  int nd = 0, total_tiles = 0;
  size_t woff = 0;
  const u16* wp[18];
  auto addw = [&](int idx, int K, int N){
    u16* dst = wsW + woff;
    tab.d[nd] = { F(idx), dst, K, N, (K>>5)*(N>>5) };
    total_tiles += tab.d[nd].ntiles;
    wp[nd] = dst;
    woff += (size_t)K*N;
    ++nd;
    return nd-1;
  };
  const int W_SA_QKV = addw(6, 256, 768);
  const int W_SA_OUT = addw(8, 256, 256);
  const int W_SA_F1  = addw(10, 512, 512);
  const int W_SA_F2  = addw(14, 512, 256);
  const int W_SS_QKV = addw(16, 256, 768);
  const int W_SS_OUT = addw(18, 256, 256);
  const int W_SS_F1  = addw(20, 512, 512);
  const int W_SS_F2  = addw(24, 512, 256);
  const int W_TT_QKV = addw(26, 256, 768);
  const int W_TT_OUT = addw(28, 256, 256);
  const int W_TT_F1  = addw(30, 512, 512);
  const int W_TT_F2  = addw(34, 512, 256);
  const int W_CA_Q   = addw(36, 256, 256);
  const int W_CA_KV  = addw(38, 256, 512);
  const int W_CA_OUT = addw(40, 256, 256);
  const int W_CA_F1  = addw(42, 512, 512);
  const int W_CA_F2  = addw(46, 512, 256);
  const int W_CF_1   = addw(48, 256, 256);
  wtcast_k<<<total_tiles, 256, 0, stream>>>(tab);

  auto mmad = [&](const float* A1, const float* A2, int K1, int wi,
                  const float* bias, const float* R, float* C,
                  int Mm, int Nn, int Kk, int relu){
    dim3 grid(Nn/128, Mm/128);
    mmad_k<<<grid, 256, 0, stream>>>(A1, A2, K1, wp[wi], bias, R, C, Mm, Nn, Kk, relu);
  };

  const int PREP_BLOCKS = (kGrp*kM*kHD)/256;   // 6144
  const int ATTN_BLOCKS = (kGrp*kM)/16;        // 1536

  // wb-relative bias/param indices: +1 qkv_b +3 out_b +5 f1_b +6 ln_g +7 ln_b +9 f2_b
  auto ffn_tail = [&](const float* xin, int wb, int wF1, int wF2, float* xout){
    mmad(xin, msgb, kD, wF1, F(wb+5), nullptr, hbuf, kRows, 2*kD, 2*kD, 0);
    lngelu_k<<<kRows, 256, 0, stream>>>(hbuf, F(wb+6), F(wb+7));
    mmad(hbuf, nullptr, 2*kD, wF2, F(wb+9), xin, xout, kRows, kD, 2*kD, 0);
  };

  auto self_block = [&](const float* xin, const float* enc, float* xout){
    const int wb = 6;
    mmad(xin, nullptr, kD, W_SA_QKV, F(wb+1), nullptr, qkvb, kRows, 3*kD, kD, 0);
    prep_self_k<<<PREP_BLOCKS, 256, 0, stream>>>(qkvb, enc, Qb, Ktb, Vb);
    attn_k<0><<<ATTN_BLOCKS, 256, 0, stream>>>(Qb, Ktb, Vb, ctxb);
    mmad(ctxb, nullptr, kD, W_SA_OUT, F(wb+3), nullptr, msgb, kRows, kD, kD, 0);
    ffn_tail(xin, wb, W_SA_F1, W_SA_F2, xout);
  };

  // 1) SelfBlock on t and s (shared sa weights)
  self_block(t_desc, t_enc, xt);
  self_block(s_desc, s_enc, xs);

  // 2) t2t block
  {
    const int wb = 26;
    mmad(xt, nullptr, kD, W_TT_QKV, F(wb+1), nullptr, qkvb, kRows, 3*kD, kD, 0);
    attn_t2t_k<<<(kB*kH*kN*kM)/256, 256, 0, stream>>>(qkvb, ctxb);
    mmad(ctxb, nullptr, kD, W_TT_OUT, F(wb+3), nullptr, msgb, kRows, kD, kD, 0);
    ffn_tail(xt, wb, W_TT_F1, W_TT_F2, xt);
  }

  // 3) s2s block
  {
    const int wb = 16;
    mmad(xs, nullptr, kD, W_SS_QKV, F(wb+1), nullptr, qkvb, kRows, 3*kD, kD, 0);
    prep_s2s_k<<<PREP_BLOCKS, 256, 0, stream>>>(qkvb, k_enc, Qb, Ktb, Vb);
    attn_s2s_k<<<ATTN_BLOCKS, 256, 0, stream>>>(Qb, Ktb, Vb, q_enc, ctxb);
    mmad(ctxb, nullptr, kD, W_SS_OUT, F(wb+3), nullptr, msgb, kRows, kD, kD, 0);
    ffn_tail(xs, wb, W_SS_F1, W_SS_F2, xs);
  }

  // 4) confidence head from xs (post-s2s)
  mmad(xs, nullptr, kD, W_CF_1, F(49), nullptr, msgb, kRows, kD, kD, 1);
  conf_dot_k<<<kRows/4, 256, 0, stream>>>(msgb, F(50), F(51), out_conf);

  // 5) cross blocks (shared ca weights)
  auto cross_block = [&](const float* d0, const float* d1, float* outp){
    mmad(d0, nullptr, kD, W_CA_Q,  F(37), nullptr, qkvb, kRows, kD, kD, 0);
    mmad(d1, nullptr, kD, W_CA_KV, F(39), nullptr, kvb,  kRows, 2*kD, kD, 0);
    prep_cross_k<<<PREP_BLOCKS, 256, 0, stream>>>(kvb, Ktb, Vb);
    attn_k<1><<<ATTN_BLOCKS, 256, 0, stream>>>(qkvb, Ktb, Vb, ctxb);
    mmad(ctxb, nullptr, kD, W_CA_OUT, F(41), nullptr, msgb, kRows, kD, kD, 0);
    mmad(d0, msgb, kD, W_CA_F1, F(43), nullptr, hbuf, kRows, 2*kD, 2*kD, 0);
    lngelu_k<<<kRows, 256, 0, stream>>>(hbuf, F(44), F(45));
    mmad(hbuf, nullptr, 2*kD, W_CA_F2, F(47), d0, outp, kRows, kD, 2*kD, 0);
  };
  cross_block(xt, xs, out_t2);
  cross_block(xs, xt, out_s2);
}

// Round 3
// 1027.267 us; speedup vs baseline: 2.0771x; 1.3550x over previous
//
#include <hip/hip_runtime.h>
#include <math.h>

// Problem constants
constexpr int kD   = 256;   // model dim
constexpr int kH   = 4;     // heads
constexpr int kHD  = 64;    // head dim
constexpr int kB   = 2;
constexpr int kN   = 6;     // views
constexpr int kM   = 512;   // keypoints (M == NS)
constexpr int kRows = kB*kN*kM;        // 6144 token rows
constexpr int kGrp  = kB*kN*kH;        // 48 attention groups
constexpr size_t kEncSlab = (size_t)kN*kM*kHD;   // 196608
constexpr size_t kQEncSlab = (size_t)kN*kN*kHD;  // 2304
constexpr float kL2E = 1.4426950408889634f;

typedef unsigned short u16;
typedef __attribute__((ext_vector_type(8))) short s16x8;
typedef __attribute__((ext_vector_type(4))) float f32x4;

__device__ __forceinline__ float wred_sum(float v){
  #pragma unroll
  for (int m=32;m>0;m>>=1) v += __shfl_xor(v, m, 64);
  return v;
}
__device__ __forceinline__ u16 f2b(float x){
  union { float f; unsigned u; } a; a.f = x;
  unsigned r = a.u + 0x7fffu + ((a.u >> 16) & 1u);
  return (u16)(r >> 16);
}

// ---------------------------------------------------------------------------
// Weight transpose+cast: W[K][N] f32 -> Wt[N][K] bf16. Batched over matrices.
// ---------------------------------------------------------------------------
struct WtDesc { const float* W; u16* Wt; int K; int N; int ntiles; };
struct WtTable { WtDesc d[18]; };

__global__ __launch_bounds__(256) void wtcast_k(WtTable tab)
{
  int t = blockIdx.x, mi = 0;
  while (t >= tab.d[mi].ntiles) { t -= tab.d[mi].ntiles; ++mi; }
  const float* W = tab.d[mi].W;
  u16* Wt = tab.d[mi].Wt;
  const int K = tab.d[mi].K, N = tab.d[mi].N;
  const int ntn = N >> 5;
  const int n0 = (t % ntn) * 32, k0 = (t / ntn) * 32;
  __shared__ float tile[32][33];
  const int tx = threadIdx.x & 31, ty = threadIdx.x >> 5;   // 32 x 8
  #pragma unroll
  for (int i = 0; i < 32; i += 8)
    tile[ty+i][tx] = W[(size_t)(k0+ty+i)*N + n0+tx];
  __syncthreads();
  #pragma unroll
  for (int i = 0; i < 32; i += 8)
    Wt[(size_t)(n0+ty+i)*K + k0+tx] = f2b(tile[tx][ty+i]);
}

// ---------------------------------------------------------------------------
// bf16 MFMA GEMM: C[M,N] f32 = concat(A1,A2)[M,K] f32 @ W (as Wt[N][K] bf16)
// 128x128 tile, BK=32, 4 waves, mfma_f32_16x16x32_bf16, XOR-swizzled LDS.
// ---------------------------------------------------------------------------
__global__ __launch_bounds__(256) void mmad_k(
    const float* __restrict__ A1, const float* __restrict__ A2, int K1,
    const u16* __restrict__ Wt, const float* __restrict__ bias,
    const float* __restrict__ R, float* __restrict__ C,
    int M, int N, int K, int doRelu)
{
  __shared__ u16 As[128*32];
  __shared__ u16 Bs[128*32];
  const int tid = threadIdx.x;
  const int lane = tid & 63, w = tid >> 6;
  const int row0 = blockIdx.y*128, col0 = blockIdx.x*128;
  const int wr = (w >> 1)*64, wc = (w & 1)*64;
  const int ar = tid >> 1;
  const int ah = tid & 1;
  const int K2 = K - K1;
  f32x4 acc[4][4] = {};

  for (int kt = 0; kt < K; kt += 32) {
    {
      const int kk = kt + ah*16;
      const float* ap = (kk < K1) ? A1 + (size_t)(row0+ar)*K1 + kk
                                  : A2 + (size_t)(row0+ar)*K2 + (kk - K1);
      union { u16 u[16]; s16x8 v[2]; } tmp;
      #pragma unroll
      for (int i = 0; i < 16; i += 4) {
        f32x4 v4 = *(const f32x4*)(ap + i);
        tmp.u[i+0] = f2b(v4.x); tmp.u[i+1] = f2b(v4.y);
        tmp.u[i+2] = f2b(v4.z); tmp.u[i+3] = f2b(v4.w);
      }
      const int sw = (ar >> 1) & 3;
      *(s16x8*)(&As[ar*32 + (((ah*2+0)^sw))*8]) = tmp.v[0];
      *(s16x8*)(&As[ar*32 + (((ah*2+1)^sw))*8]) = tmp.v[1];
    }
    {
      const u16* bp = Wt + (size_t)(col0+ar)*K + kt + ah*16;
      s16x8 b0 = *(const s16x8*)(bp);
      s16x8 b1 = *(const s16x8*)(bp + 8);
      const int sw = (ar >> 1) & 3;
      *(s16x8*)(&Bs[ar*32 + (((ah*2+0)^sw))*8]) = b0;
      *(s16x8*)(&Bs[ar*32 + (((ah*2+1)^sw))*8]) = b1;
    }
    __syncthreads();
    s16x8 af[4], bfv[4];
    #pragma unroll
    for (int fm = 0; fm < 4; ++fm) {
      const int r = wr + fm*16 + (lane & 15);
      const int g = (lane >> 4) ^ ((r >> 1) & 3);
      af[fm] = *(const s16x8*)(&As[r*32 + g*8]);
    }
    #pragma unroll
    for (int fn = 0; fn < 4; ++fn) {
      const int c = wc + fn*16 + (lane & 15);
      const int g = (lane >> 4) ^ ((c >> 1) & 3);
      bfv[fn] = *(const s16x8*)(&Bs[c*32 + g*8]);
    }
    #pragma unroll
    for (int fm = 0; fm < 4; ++fm)
      #pragma unroll
      for (int fn = 0; fn < 4; ++fn)
        acc[fm][fn] = __builtin_amdgcn_mfma_f32_16x16x32_bf16(af[fm], bfv[fn], acc[fm][fn], 0, 0, 0);
    __syncthreads();
  }

  #pragma unroll
  for (int fm = 0; fm < 4; ++fm) {
    const int rbase = row0 + wr + fm*16 + (lane >> 4)*4;
    #pragma unroll
    for (int fn = 0; fn < 4; ++fn) {
      const int cc = col0 + wc + fn*16 + (lane & 15);
      const float bv = bias[cc];
      #pragma unroll
      for (int j = 0; j < 4; ++j) {
        const size_t idx = (size_t)(rbase + j)*N + cc;
        float v = acc[fm][fn][j] + bv;
        if (R) v += R[idx];
        if (doRelu) v = fmaxf(v, 0.f);
        C[idx] = v;
      }
    }
  }
}

// ---------------------------------------------------------------------------
// Preps: emit bf16 K [g][key][64], bf16 Vt [g][64][key] (LDS transpose),
// and Q (self: roped+prescaled bf16; s2s: raw f32).
// Grid: 48 groups x 8 i-blocks = 384 blocks, 256 threads.
// ---------------------------------------------------------------------------
__global__ __launch_bounds__(256) void prep_self_mm_k(
    const float* __restrict__ qkv, const float* __restrict__ enc,
    u16* __restrict__ Qb, u16* __restrict__ Kb, u16* __restrict__ Vt)
{
  __shared__ float vs[64][65];
  const int g = blockIdx.x >> 3, i0 = (blockIdx.x & 7)*64;
  const int h = g & 3, bn = g >> 2, n = bn % kN;
  const int c = threadIdx.x & 63, t4 = threadIdx.x >> 6;
  const float sgn = (c & 1) ? 1.f : -1.f;
  #pragma unroll 4
  for (int rr = 0; rr < 16; ++rr) {
    const int il = rr*4 + t4;
    const int i = i0 + il;
    const float* base = qkv + ((size_t)(bn*kM + i))*768 + h*192;
    const float q = base[c*3+0], k = base[c*3+1], v = base[c*3+2];
    const float qp = base[(c^1)*3+0], kp = base[(c^1)*3+1];
    const size_t eo = ((size_t)(n*kM + i))*kHD + c;
    const float e0 = enc[eo], e1 = enc[kEncSlab + eo];
    Qb[((size_t)g*kM + i)*kHD + c] = f2b((q*e0 + sgn*qp*e1)*0.125f);
    Kb[((size_t)g*kM + i)*kHD + c] = f2b(k*e0 + sgn*kp*e1);
    vs[il][c] = v;
  }
  __syncthreads();
  const int il2 = threadIdx.x & 63;
  #pragma unroll 4
  for (int rr = 0; rr < 16; ++rr) {
    const int cc = rr*4 + t4;
    Vt[((size_t)g*kHD + cc)*kM + i0 + il2] = f2b(vs[il2][cc]);
  }
}

__global__ __launch_bounds__(256) void prep_s2s_mm_k(
    const float* __restrict__ qkv, const float* __restrict__ kenc,
    float* __restrict__ Qs, u16* __restrict__ Kb, u16* __restrict__ Vt)
{
  __shared__ float vs[64][65];
  const int g = blockIdx.x >> 3, i0 = (blockIdx.x & 7)*64;   // g = bh*6+view
  const int view = g % kN, bh = g / kN;
  const int h = bh & 3, b = bh >> 2;
  const int c = threadIdx.x & 63, t4 = threadIdx.x >> 6;
  const float sgn = (c & 1) ? 1.f : -1.f;
  #pragma unroll 4
  for (int rr = 0; rr < 16; ++rr) {
    const int il = rr*4 + t4;
    const int i = i0 + il;
    const float* base = qkv + ((size_t)((b*kN+view)*kM + i))*768 + h*192;
    const float q = base[c*3+0], k = base[c*3+1], v = base[c*3+2];
    const float kp = base[(c^1)*3+1];
    const size_t eo = ((size_t)(view*kM + i))*kHD + c;
    const float e0 = kenc[eo], e1 = kenc[kEncSlab + eo];
    Qs[((size_t)g*kM + i)*kHD + c] = q;
    Kb[((size_t)g*kM + i)*kHD + c] = f2b(k*e0 + sgn*kp*e1);
    vs[il][c] = v;
  }
  __syncthreads();
  const int il2 = threadIdx.x & 63;
  #pragma unroll 4
  for (int rr = 0; rr < 16; ++rr) {
    const int cc = rr*4 + t4;
    Vt[((size_t)g*kHD + cc)*kM + i0 + il2] = f2b(vs[il2][cc]);
  }
}

__global__ __launch_bounds__(256) void prep_cross_mm_k(
    const float* __restrict__ kv, u16* __restrict__ Kb, u16* __restrict__ Vt)
{
  __shared__ float vs[64][65];
  const int g = blockIdx.x >> 3, i0 = (blockIdx.x & 7)*64;
  const int h = g & 3, bn = g >> 2;
  const int c = threadIdx.x & 63, t4 = threadIdx.x >> 6;
  #pragma unroll 4
  for (int rr = 0; rr < 16; ++rr) {
    const int il = rr*4 + t4;
    const int i = i0 + il;
    const float* base = kv + ((size_t)(bn*kM + i))*512 + h*128;
    Kb[((size_t)g*kM + i)*kHD + c] = f2b(base[c*2+0]);
    vs[il][c] = base[c*2+1];
  }
  __syncthreads();
  const int il2 = threadIdx.x & 63;
  #pragma unroll 4
  for (int rr = 0; rr < 16; ++rr) {
    const int cc = rr*4 + t4;
    Vt[((size_t)g*kHD + cc)*kM + i0 + il2] = f2b(vs[il2][cc]);
  }
}

// ---------------------------------------------------------------------------
// MFMA attention core: one wave, 16 q-rows, 512 keys, online softmax.
// Swapped QK^T (mfma(K,Q) -> S^T: col=q, row=key), P routed through a small
// XOR-swizzled per-wave LDS buffer to the PV A-fragment layout.
// Q frags are pre-scaled by 0.125.
// ---------------------------------------------------------------------------
__device__ __forceinline__ void attn_core(
    const u16* __restrict__ Kg, const u16* __restrict__ Vg,
    s16x8 qf0, s16x8 qf1, u16* __restrict__ pw,   // pw: this wave's [16][40] u16
    int qr, int hi, f32x4 acc[4], float& m, float& l)
{
  const int sq = qr & 3;
  for (int kc = 0; kc < 16; ++kc) {
    const int k0 = kc*32;
    f32x4 st[2];
    #pragma unroll
    for (int t = 0; t < 2; ++t) {
      const u16* kp = Kg + ((size_t)(k0 + t*16 + qr))*kHD + hi*8;
      s16x8 a0 = *(const s16x8*)(kp);
      s16x8 a1 = *(const s16x8*)(kp + 32);
      f32x4 z = {0.f, 0.f, 0.f, 0.f};
      z = __builtin_amdgcn_mfma_f32_16x16x32_bf16(a0, qf0, z, 0, 0, 0);
      z = __builtin_amdgcn_mfma_f32_16x16x32_bf16(a1, qf1, z, 0, 0, 0);
      st[t] = z;
    }
    float mloc = fmaxf(fmaxf(fmaxf(st[0][0], st[0][1]), fmaxf(st[0][2], st[0][3])),
                       fmaxf(fmaxf(st[1][0], st[1][1]), fmaxf(st[1][2], st[1][3])));
    mloc = fmaxf(mloc, __shfl_xor(mloc, 16));
    mloc = fmaxf(mloc, __shfl_xor(mloc, 32));
    const float mn = fmaxf(m, mloc);
    const float r = exp2f((m - mn)*kL2E);
    m = mn;
    float p[8], ls = 0.f;
    #pragma unroll
    for (int t = 0; t < 2; ++t)
      #pragma unroll
      for (int j = 0; j < 4; ++j) {
        const float pv = exp2f((st[t][j] - mn)*kL2E);
        p[t*4+j] = pv; ls += pv;
      }
    l = l*r + ls;
    const float rr0 = __shfl(r, hi*4+0), rr1 = __shfl(r, hi*4+1);
    const float rr2 = __shfl(r, hi*4+2), rr3 = __shfl(r, hi*4+3);
    #pragma unroll
    for (int db = 0; db < 4; ++db) {
      acc[db][0] *= rr0; acc[db][1] *= rr1; acc[db][2] *= rr2; acc[db][3] *= rr3;
    }
    union { u16 u[8]; uint2 d[2]; } pb;
    #pragma unroll
    for (int j = 0; j < 8; ++j) pb.u[j] = f2b(p[j]);
    // lane's 4 keys of subtile t live in 8B half (hi&1) of granule (t*2+(hi>>1))^sq
    *(uint2*)&pw[qr*40 + (((hi>>1)    ) ^ sq)*8 + (hi&1)*4] = pb.d[0];
    *(uint2*)&pw[qr*40 + ((2+(hi>>1)) ^ sq)*8 + (hi&1)*4] = pb.d[1];
    const s16x8 pa = *(const s16x8*)&pw[qr*40 + (hi ^ sq)*8];
    #pragma unroll
    for (int db = 0; db < 4; ++db) {
      const u16* vp = Vg + ((size_t)(db*16 + qr))*kM + k0 + hi*8;
      const s16x8 vf = *(const s16x8*)(vp);
      acc[db] = __builtin_amdgcn_mfma_f32_16x16x32_bf16(pa, vf, acc[db], 0, 0, 0);
    }
  }
}

// self (CROSSQ=0: Qb bf16 pre-roped+scaled) / cross (CROSSQ=1: Qf f32 rows)
template<int CROSSQ>
__global__ __launch_bounds__(256) void attn_mm_k(
    const u16* __restrict__ Qb, const float* __restrict__ Qf,
    const u16* __restrict__ Kb, const u16* __restrict__ Vt,
    float* __restrict__ ctx)
{
  __shared__ u16 p_lds[4][16][40];
  const int w = threadIdx.x >> 6, lane = threadIdx.x & 63;
  const int bij = (blockIdx.x & 7)*48 + (blockIdx.x >> 3);   // XCD-bijective
  const int g = bij >> 3, qblk = bij & 7;
  const int h = g & 3, bn = g >> 2;
  const int q0 = qblk*64 + w*16;
  const int qr = lane & 15, hi = lane >> 4;

  s16x8 qf0, qf1;
  if (CROSSQ) {
    const float* qp = Qf + ((size_t)(bn*kM + q0 + qr))*kD + h*kHD + hi*8;
    union { u16 u[8]; s16x8 v; } A, B;
    f32x4 x0 = *(const f32x4*)(qp),    x1 = *(const f32x4*)(qp+4);
    f32x4 y0 = *(const f32x4*)(qp+32), y1 = *(const f32x4*)(qp+36);
    #pragma unroll
    for (int j = 0; j < 4; ++j) {
      A.u[j] = f2b(x0[j]*0.125f); A.u[4+j] = f2b(x1[j]*0.125f);
      B.u[j] = f2b(y0[j]*0.125f); B.u[4+j] = f2b(y1[j]*0.125f);
    }
    qf0 = A.v; qf1 = B.v;
  } else {
    const u16* qp = Qb + ((size_t)g*kM + q0 + qr)*kHD + hi*8;
    qf0 = *(const s16x8*)(qp);
    qf1 = *(const s16x8*)(qp + 32);
  }

  const u16* Kg = Kb + (size_t)g*kM*kHD;
  const u16* Vg = Vt + (size_t)g*kHD*kM;
  f32x4 acc[4] = {};
  float m = -1e30f, l = 0.f;
  attn_core(Kg, Vg, qf0, qf1, &p_lds[w][0][0], qr, hi, acc, m, l);

  l += __shfl_xor(l, 16); l += __shfl_xor(l, 32);
  const float li = 1.f/l;
  const float l0 = __shfl(li, hi*4+0), l1 = __shfl(li, hi*4+1);
  const float l2 = __shfl(li, hi*4+2), l3 = __shfl(li, hi*4+3);
  #pragma unroll
  for (int db = 0; db < 4; ++db) {
    const size_t base = ((size_t)(bn*kM + q0 + hi*4))*kD + h*kHD + db*16 + qr;
    ctx[base + 0*kD] = acc[db][0]*l0;
    ctx[base + 1*kD] = acc[db][1]*l1;
    ctx[base + 2*kD] = acc[db][2]*l2;
    ctx[base + 3*kD] = acc[db][3]*l3;
  }
}

__device__ __forceinline__ void rope4(const f32x4 x, const f32x4 e0, const f32x4 e1, float o[4])
{
  o[0] = x[0]*e0[0] - x[1]*e1[0];
  o[1] = x[1]*e0[1] + x[0]*e1[1];
  o[2] = x[2]*e0[2] - x[3]*e1[2];
  o[3] = x[3]*e0[3] + x[2]*e1[3];
}

// s2s: per wave, 5 off-diagonal (i,j) attentions of output column `col`,
// q roped per pair, mean folded (x0.2).
__global__ __launch_bounds__(256) void attn_s2s_mm_k(
    const float* __restrict__ Qraw, const u16* __restrict__ Kb,
    const u16* __restrict__ Vt, const float* __restrict__ qenc,
    float* __restrict__ ctx)
{
  __shared__ u16 p_lds[4][16][40];
  const int w = threadIdx.x >> 6, lane = threadIdx.x & 63;
  const int bij = (blockIdx.x & 7)*48 + (blockIdx.x >> 3);   // XCD chunk == bh
  const int G = bij >> 3, qblk = bij & 7;
  const int bh = G / kN, col = G % kN;
  const int q0 = qblk*64 + w*16;
  const int qr = lane & 15, hi = lane >> 4;
  f32x4 macc[4] = {};

  for (int r5 = 0; r5 < 5; ++r5) {
    const int e  = r5*6 + col;
    const int iv = e/5;
    const int j0 = e%5;
    const int jv = j0 + (j0 >= iv ? 1 : 0);
    // build roped, 0.125-scaled q frags
    s16x8 qf0, qf1;
    {
      const float* qp = Qraw + ((size_t)(bh*kN + jv)*kM + q0 + qr)*kHD + hi*8;
      const float* ep = qenc + ((size_t)(iv*kN + jv))*kHD + hi*8;
      union { u16 u[8]; s16x8 v; } A, B;
      float o[4];
      rope4(*(const f32x4*)(qp),   *(const f32x4*)(ep),   *(const f32x4*)(ep+kQEncSlab), o);
      #pragma unroll
      for (int j = 0; j < 4; ++j) A.u[j] = f2b(o[j]*0.125f);
      rope4(*(const f32x4*)(qp+4), *(const f32x4*)(ep+4), *(const f32x4*)(ep+kQEncSlab+4), o);
      #pragma unroll
      for (int j = 0; j < 4; ++j) A.u[4+j] = f2b(o[j]*0.125f);
      rope4(*(const f32x4*)(qp+32), *(const f32x4*)(ep+32), *(const f32x4*)(ep+kQEncSlab+32), o);
      #pragma unroll
      for (int j = 0; j < 4; ++j) B.u[j] = f2b(o[j]*0.125f);
      rope4(*(const f32x4*)(qp+36), *(const f32x4*)(ep+36), *(const f32x4*)(ep+kQEncSlab+36), o);
      #pragma unroll
      for (int j = 0; j < 4; ++j) B.u[4+j] = f2b(o[j]*0.125f);
      qf0 = A.v; qf1 = B.v;
    }
    const int g2 = bh*kN + iv;
    const u16* Kg = Kb + (size_t)g2*kM*kHD;
    const u16* Vg = Vt + (size_t)g2*kHD*kM;
    f32x4 acc[4] = {};
    float m = -1e30f, l = 0.f;
    attn_core(Kg, Vg, qf0, qf1, &p_lds[w][0][0], qr, hi, acc, m, l);
    l += __shfl_xor(l, 16); l += __shfl_xor(l, 32);
    const float li = 0.2f/l;
    const float l0 = __shfl(li, hi*4+0), l1 = __shfl(li, hi*4+1);
    const float l2 = __shfl(li, hi*4+2), l3 = __shfl(li, hi*4+3);
    #pragma unroll
    for (int db = 0; db < 4; ++db) {
      macc[db][0] += acc[db][0]*l0;
      macc[db][1] += acc[db][1]*l1;
      macc[db][2] += acc[db][2]*l2;
      macc[db][3] += acc[db][3]*l3;
    }
  }
  const int b = bh >> 2, h = bh & 3;
  #pragma unroll
  for (int db = 0; db < 4; ++db) {
    const size_t base = ((size_t)((b*kN + col)*kM + q0 + hi*4))*kD + h*kHD + db*16 + qr;
    ctx[base + 0*kD] = macc[db][0];
    ctx[base + 1*kD] = macc[db][1];
    ctx[base + 2*kD] = macc[db][2];
    ctx[base + 3*kD] = macc[db][3];
  }
}

// t2t attention: tiny sequence (N=6). One thread per (b,h,nq,mpos).
__global__ void attn_t2t_k(const float* __restrict__ qkv, float* __restrict__ ctx)
{
  const int idx = blockIdx.x*256 + threadIdx.x;
  const int mpos = idx & 511;
  int t = idx >> 9;
  const int nq = t % kN;
  const int bh = t / kN;
  const int h = bh & 3, b = bh >> 2;
  const float* kb[kN];
  #pragma unroll
  for (int nk=0;nk<kN;++nk)
    kb[nk] = qkv + ((size_t)(b*kN+nk)*kM + mpos)*768 + h*192;
  const float* qb = kb[nq];
  float sim[kN] = {0,0,0,0,0,0};
  for (int c=0;c<64;++c){
    const float qc = qb[c*3+0];
    #pragma unroll
    for (int nk=0;nk<kN;++nk) sim[nk] = fmaf(qc, kb[nk][c*3+1], sim[nk]);
  }
  float mx = -1e30f;
  #pragma unroll
  for (int nk=0;nk<kN;++nk){ sim[nk] *= 0.125f; mx = fmaxf(mx, sim[nk]); }
  float p[kN], s = 0.f;
  #pragma unroll
  for (int nk=0;nk<kN;++nk){ p[nk] = expf(sim[nk]-mx); s += p[nk]; }
  const float invs = 1.f/s;
  float* outp = ctx + ((size_t)(b*kN+nq)*kM + mpos)*kD + h*kHD;
  for (int c=0;c<64;++c){
    float ov = 0.f;
    #pragma unroll
    for (int nk=0;nk<kN;++nk) ov = fmaf(p[nk], kb[nk][c*3+2], ov);
    outp[c] = ov*invs;
  }
}

// LayerNorm(512) + exact GELU, in place. One block per row.
__global__ __launch_bounds__(256) void lngelu_k(float* __restrict__ hbuf,
    const float* __restrict__ g, const float* __restrict__ b)
{
  const int row = blockIdx.x;
  const int tid = threadIdx.x;
  float* x = hbuf + (size_t)row*512;
  const float v0 = x[tid], v1 = x[tid+256];
  const int w = tid >> 6, lane = tid & 63;
  __shared__ float red[2][4];
  const float s1 = wred_sum(v0+v1);
  const float s2 = wred_sum(v0*v0+v1*v1);
  if (lane == 0){ red[0][w]=s1; red[1][w]=s2; }
  __syncthreads();
  const float mean = (red[0][0]+red[0][1]+red[0][2]+red[0][3]) * (1.f/512.f);
  const float ms   = (red[1][0]+red[1][1]+red[1][2]+red[1][3]) * (1.f/512.f);
  const float rs = rsqrtf(ms - mean*mean + 1e-5f);
  const float y0 = (v0-mean)*rs*g[tid]     + b[tid];
  const float y1 = (v1-mean)*rs*g[tid+256] + b[tid+256];
  x[tid]     = 0.5f*y0*(1.f+erff(y0*0.70710678118654752f));
  x[tid+256] = 0.5f*y1*(1.f+erff(y1*0.70710678118654752f));
}

__global__ void conf_dot_k(const float* __restrict__ tmp, const float* __restrict__ w2,
                           const float* __restrict__ b2, float* __restrict__ out)
{
  const int w = threadIdx.x >> 6, lane = threadIdx.x & 63;
  const int row = blockIdx.x*4 + w;
  const float* t = tmp + (size_t)row*kD;
  float s = 0.f;
  #pragma unroll
  for (int j=0;j<4;++j) s = fmaf(t[lane+j*64], w2[lane+j*64], s);
  s = wred_sum(s);
  if (lane == 0) out[row] = s + b2[0];
}

// ---------------------------------------------------------------------------
extern "C" void kernel_launch(void* const* d_in, const int* in_sizes, int n_in,
                              void* d_out, int out_size, void* d_ws, size_t ws_size,
                              hipStream_t stream)
{
  auto F = [&](int i){ return (const float*)d_in[i]; };
  const float* t_desc = F(0);
  const float* s_desc = F(1);
  const float* t_enc  = F(2);
  const float* s_enc  = F(3);
  const float* q_enc  = F(4);
  const float* k_enc  = F(5);

  float* ws = (float*)d_ws;
  const size_t TOK = (size_t)kRows*kD;      // 1,572,864
  float* xt   = ws;
  float* xs   = ws + TOK;
  float* qkvb = ws + 2*TOK;                 // 3*TOK floats
  float* ctxb = ws + 5*TOK;
  float* msgb = ws + 6*TOK;
  float* hbuf = ws + 7*TOK;                 // 2*TOK floats
  float* Qs2s = ws + 9*TOK;                 // TOK floats
  u16*   Qb16 = (u16*)(ws + 10*TOK);        // TOK u16
  u16*   Kb16 = Qb16 + TOK;                 // TOK u16
  u16*   Vt16 = Kb16 + TOK;                 // TOK u16
  u16*   wsW  = Vt16 + TOK;                 // bf16 transposed weights
  float* kvb  = qkvb + TOK;

  float* out_t2   = (float*)d_out;
  float* out_s2   = out_t2 + TOK;
  float* out_conf = out_t2 + 2*TOK;

  // ---- weight transpose+cast table (once per call) ----
  WtTable tab;
  int nd = 0, total_tiles = 0;
  size_t woff = 0;
  const u16* wp[18];
  auto addw = [&](int idx, int K, int N){
    u16* dst = wsW + woff;
    tab.d[nd] = { F(idx), dst, K, N, (K>>5)*(N>>5) };
    total_tiles += tab.d[nd].ntiles;
    wp[nd] = dst;
    woff += (size_t)K*N;
    ++nd;
    return nd-1;
  };
  const int W_SA_QKV = addw(6, 256, 768);
  const int W_SA_OUT = addw(8, 256, 256);
  const int W_SA_F1  = addw(10, 512, 512);
  const int W_SA_F2  = addw(14, 512, 256);
  const int W_SS_QKV = addw(16, 256, 768);
  const int W_SS_OUT = addw(18, 256, 256);
  const int W_SS_F1  = addw(20, 512, 512);
  const int W_SS_F2  = addw(24, 512, 256);
  const int W_TT_QKV = addw(26, 256, 768);
  const int W_TT_OUT = addw(28, 256, 256);
  const int W_TT_F1  = addw(30, 512, 512);
  const int W_TT_F2  = addw(34, 512, 256);
  const int W_CA_Q   = addw(36, 256, 256);
  const int W_CA_KV  = addw(38, 256, 512);
  const int W_CA_OUT = addw(40, 256, 256);
  const int W_CA_F1  = addw(42, 512, 512);
  const int W_CA_F2  = addw(46, 512, 256);
  const int W_CF_1   = addw(48, 256, 256);
  wtcast_k<<<total_tiles, 256, 0, stream>>>(tab);

  auto mmad = [&](const float* A1, const float* A2, int K1, int wi,
                  const float* bias, const float* R, float* C,
                  int Mm, int Nn, int Kk, int relu){
    dim3 grid(Nn/128, Mm/128);
    mmad_k<<<grid, 256, 0, stream>>>(A1, A2, K1, wp[wi], bias, R, C, Mm, Nn, Kk, relu);
  };

  const int AB = kGrp*8;   // 384 blocks for preps and attention

  auto ffn_tail = [&](const float* xin, int wb, int wF1, int wF2, float* xout){
    mmad(xin, msgb, kD, wF1, F(wb+5), nullptr, hbuf, kRows, 2*kD, 2*kD, 0);
    lngelu_k<<<kRows, 256, 0, stream>>>(hbuf, F(wb+6), F(wb+7));
    mmad(hbuf, nullptr, 2*kD, wF2, F(wb+9), xin, xout, kRows, kD, 2*kD, 0);
  };

  auto self_block = [&](const float* xin, const float* enc, float* xout){
    const int wb = 6;
    mmad(xin, nullptr, kD, W_SA_QKV, F(wb+1), nullptr, qkvb, kRows, 3*kD, kD, 0);
    prep_self_mm_k<<<AB, 256, 0, stream>>>(qkvb, enc, Qb16, Kb16, Vt16);
    attn_mm_k<0><<<AB, 256, 0, stream>>>(Qb16, nullptr, Kb16, Vt16, ctxb);
    mmad(ctxb, nullptr, kD, W_SA_OUT, F(wb+3), nullptr, msgb, kRows, kD, kD, 0);
    ffn_tail(xin, wb, W_SA_F1, W_SA_F2, xout);
  };

  // 1) SelfBlock on t and s (shared sa weights)
  self_block(t_desc, t_enc, xt);
  self_block(s_desc, s_enc, xs);

  // 2) t2t block
  {
    const int wb = 26;
    mmad(xt, nullptr, kD, W_TT_QKV, F(wb+1), nullptr, qkvb, kRows, 3*kD, kD, 0);
    attn_t2t_k<<<(kB*kH*kN*kM)/256, 256, 0, stream>>>(qkvb, ctxb);
    mmad(ctxb, nullptr, kD, W_TT_OUT, F(wb+3), nullptr, msgb, kRows, kD, kD, 0);
    ffn_tail(xt, wb, W_TT_F1, W_TT_F2, xt);
  }

  // 3) s2s block
  {
    const int wb = 16;
    mmad(xs, nullptr, kD, W_SS_QKV, F(wb+1), nullptr, qkvb, kRows, 3*kD, kD, 0);
    prep_s2s_mm_k<<<AB, 256, 0, stream>>>(qkvb, k_enc, Qs2s, Kb16, Vt16);
    attn_s2s_mm_k<<<AB, 256, 0, stream>>>(Qs2s, Kb16, Vt16, q_enc, ctxb);
    mmad(ctxb, nullptr, kD, W_SS_OUT, F(wb+3), nullptr, msgb, kRows, kD, kD, 0);
    ffn_tail(xs, wb, W_SS_F1, W_SS_F2, xs);
  }

  // 4) confidence head from xs (post-s2s)
  mmad(xs, nullptr, kD, W_CF_1, F(49), nullptr, msgb, kRows, kD, kD, 1);
  conf_dot_k<<<kRows/4, 256, 0, stream>>>(msgb, F(50), F(51), out_conf);

  // 5) cross blocks (shared ca weights)
  auto cross_block = [&](const float* d0, const float* d1, float* outp){
    mmad(d0, nullptr, kD, W_CA_Q,  F(37), nullptr, qkvb, kRows, kD, kD, 0);
    mmad(d1, nullptr, kD, W_CA_KV, F(39), nullptr, kvb,  kRows, 2*kD, kD, 0);
    prep_cross_mm_k<<<AB, 256, 0, stream>>>(kvb, Kb16, Vt16);
    attn_mm_k<1><<<AB, 256, 0, stream>>>(nullptr, qkvb, Kb16, Vt16, ctxb);
    mmad(ctxb, nullptr, kD, W_CA_OUT, F(41), nullptr, msgb, kRows, kD, kD, 0);
    mmad(d0, msgb, kD, W_CA_F1, F(43), nullptr, hbuf, kRows, 2*kD, 2*kD, 0);
    lngelu_k<<<kRows, 256, 0, stream>>>(hbuf, F(44), F(45));
    mmad(hbuf, nullptr, 2*kD, W_CA_F2, F(47), d0, outp, kRows, kD, 2*kD, 0);
  };
  cross_block(xt, xs, out_t2);
  cross_block(xs, xt, out_s2);
}

// Round 4
// 594.985 us; speedup vs baseline: 3.5863x; 1.7265x over previous
//
#include <hip/hip_runtime.h>
#include <math.h>

// Problem constants
constexpr int kD   = 256;   // model dim
constexpr int kH   = 4;     // heads
constexpr int kHD  = 64;    // head dim
constexpr int kB   = 2;
constexpr int kN   = 6;     // views
constexpr int kM   = 512;   // keypoints (M == NS)
constexpr int kRowsH = kB*kN*kM;          // 6144 rows per half (t or s)
constexpr int kRows  = 2*kRowsH;          // 12288 merged rows
constexpr int kGrpH  = kB*kN*kH;          // 48 attention groups per half
constexpr int kGrp   = 2*kGrpH;           // 96 merged groups
constexpr size_t kTOK = (size_t)kRowsH*kD;        // 1,572,864
constexpr size_t kEncSlab = (size_t)kN*kM*kHD;    // 196608
constexpr size_t kQEncSlab = (size_t)kN*kN*kHD;   // 2304
constexpr float kL2E = 1.4426950408889634f;

typedef unsigned short u16;
typedef __attribute__((ext_vector_type(8))) short s16x8;
typedef __attribute__((ext_vector_type(4))) float f32x4;

__device__ __forceinline__ float wred_sum(float v){
  #pragma unroll
  for (int m=32;m>0;m>>=1) v += __shfl_xor(v, m, 64);
  return v;
}
__device__ __forceinline__ u16 f2b(float x){
  union { float f; unsigned u; } a; a.f = x;
  unsigned r = a.u + 0x7fffu + ((a.u >> 16) & 1u);
  return (u16)(r >> 16);
}
__device__ __forceinline__ float b2f(u16 x){
  union { unsigned u; float f; } a; a.u = ((unsigned)x) << 16;
  return a.f;
}

// ---------------------------------------------------------------------------
// Weight transpose+cast: W[K][N] f32 -> Wt[N][K] bf16. Batched over matrices.
// ---------------------------------------------------------------------------
struct WtDesc { const float* W; u16* Wt; int K; int N; int ntiles; };
struct WtTable { WtDesc d[18]; };

__global__ __launch_bounds__(256) void wtcast_k(WtTable tab)
{
  int t = blockIdx.x, mi = 0;
  while (t >= tab.d[mi].ntiles) { t -= tab.d[mi].ntiles; ++mi; }
  const float* W = tab.d[mi].W;
  u16* Wt = tab.d[mi].Wt;
  const int K = tab.d[mi].K, N = tab.d[mi].N;
  const int ntn = N >> 5;
  const int n0 = (t % ntn) * 32, k0 = (t / ntn) * 32;
  __shared__ float tile[32][33];
  const int tx = threadIdx.x & 31, ty = threadIdx.x >> 5;
  #pragma unroll
  for (int i = 0; i < 32; i += 8)
    tile[ty+i][tx] = W[(size_t)(k0+ty+i)*N + n0+tx];
  __syncthreads();
  #pragma unroll
  for (int i = 0; i < 32; i += 8)
    Wt[(size_t)(n0+ty+i)*K + k0+tx] = f2b(tile[tx][ty+i]);
}

// ---------------------------------------------------------------------------
// bf16 MFMA GEMM, dual row-segment (rows<Mh use seg a, else seg b).
// A1/A2 (K-concat at K1), each f32 or bf16 per template. C f32 or bf16.
// 128x128 tile, BK=32, 4 waves, mfma_f32_16x16x32_bf16, XOR-swizzled LDS.
// ---------------------------------------------------------------------------
template<bool A1B, bool A2B, bool CB>
__global__ __launch_bounds__(256) void mmad_k(
    const void* __restrict__ A1a, const void* __restrict__ A1b,
    const void* __restrict__ A2a, const void* __restrict__ A2b, int K1,
    const u16* __restrict__ Wa, const u16* __restrict__ Wb,
    const float* __restrict__ bia, const float* __restrict__ bib,
    const float* __restrict__ Ra, const float* __restrict__ Rb,
    void* __restrict__ Cp, int N, int K, int Mh, int doRelu)
{
  __shared__ u16 As[128*32];
  __shared__ u16 Bs[128*32];
  const int tid = threadIdx.x;
  const int lane = tid & 63, w = tid >> 6;
  const int row0 = blockIdx.y*128, col0 = blockIdx.x*128;
  const bool sec = (row0 >= Mh);
  const int lr0 = sec ? row0 - Mh : row0;
  const void* A1 = sec ? A1b : A1a;
  const void* A2 = sec ? A2b : A2a;
  const u16* Wt  = sec ? Wb : Wa;
  const float* bias = sec ? bib : bia;
  const float* R = sec ? Rb : Ra;
  const int wr = (w >> 1)*64, wc = (w & 1)*64;
  const int ar = tid >> 1, ah = tid & 1;
  const int K2 = K - K1;
  f32x4 acc[4][4] = {};

  for (int kt = 0; kt < K; kt += 32) {
    const int kk = kt + ah*16;
    union { u16 u[16]; s16x8 v[2]; } tmp;
    if (kk < K1) {
      if constexpr (A1B) {
        const u16* ap = (const u16*)A1 + (size_t)(lr0+ar)*K1 + kk;
        tmp.v[0] = *(const s16x8*)ap; tmp.v[1] = *(const s16x8*)(ap+8);
      } else {
        const float* ap = (const float*)A1 + (size_t)(lr0+ar)*K1 + kk;
        #pragma unroll
        for (int i = 0; i < 16; i += 4) {
          f32x4 v4 = *(const f32x4*)(ap + i);
          tmp.u[i+0]=f2b(v4.x); tmp.u[i+1]=f2b(v4.y); tmp.u[i+2]=f2b(v4.z); tmp.u[i+3]=f2b(v4.w);
        }
      }
    } else {
      if constexpr (A2B) {
        const u16* ap = (const u16*)A2 + (size_t)(lr0+ar)*K2 + (kk - K1);
        tmp.v[0] = *(const s16x8*)ap; tmp.v[1] = *(const s16x8*)(ap+8);
      } else {
        const float* ap = (const float*)A2 + (size_t)(lr0+ar)*K2 + (kk - K1);
        #pragma unroll
        for (int i = 0; i < 16; i += 4) {
          f32x4 v4 = *(const f32x4*)(ap + i);
          tmp.u[i+0]=f2b(v4.x); tmp.u[i+1]=f2b(v4.y); tmp.u[i+2]=f2b(v4.z); tmp.u[i+3]=f2b(v4.w);
        }
      }
    }
    const int sw = (ar >> 1) & 3;
    *(s16x8*)(&As[ar*32 + ((ah*2+0)^sw)*8]) = tmp.v[0];
    *(s16x8*)(&As[ar*32 + ((ah*2+1)^sw)*8]) = tmp.v[1];
    {
      const u16* bp = Wt + (size_t)(col0+ar)*K + kt + ah*16;
      s16x8 b0 = *(const s16x8*)(bp);
      s16x8 b1 = *(const s16x8*)(bp + 8);
      *(s16x8*)(&Bs[ar*32 + ((ah*2+0)^sw)*8]) = b0;
      *(s16x8*)(&Bs[ar*32 + ((ah*2+1)^sw)*8]) = b1;
    }
    __syncthreads();
    s16x8 af[4], bfv[4];
    #pragma unroll
    for (int fm = 0; fm < 4; ++fm) {
      const int r = wr + fm*16 + (lane & 15);
      const int g = (lane >> 4) ^ ((r >> 1) & 3);
      af[fm] = *(const s16x8*)(&As[r*32 + g*8]);
    }
    #pragma unroll
    for (int fn = 0; fn < 4; ++fn) {
      const int c = wc + fn*16 + (lane & 15);
      const int g = (lane >> 4) ^ ((c >> 1) & 3);
      bfv[fn] = *(const s16x8*)(&Bs[c*32 + g*8]);
    }
    #pragma unroll
    for (int fm = 0; fm < 4; ++fm)
      #pragma unroll
      for (int fn = 0; fn < 4; ++fn)
        acc[fm][fn] = __builtin_amdgcn_mfma_f32_16x16x32_bf16(af[fm], bfv[fn], acc[fm][fn], 0, 0, 0);
    __syncthreads();
  }

  #pragma unroll
  for (int fm = 0; fm < 4; ++fm) {
    const int ro = wr + fm*16 + (lane >> 4)*4;
    #pragma unroll
    for (int fn = 0; fn < 4; ++fn) {
      const int cc = col0 + wc + fn*16 + (lane & 15);
      const float bv = bias[cc];
      #pragma unroll
      for (int j = 0; j < 4; ++j) {
        float v = acc[fm][fn][j] + bv;
        if (R) v += R[(size_t)(lr0 + ro + j)*N + cc];
        if (doRelu) v = fmaxf(v, 0.f);
        const size_t idx = (size_t)(row0 + ro + j)*N + cc;
        if constexpr (CB) ((u16*)Cp)[idx] = f2b(v);
        else              ((float*)Cp)[idx] = v;
      }
    }
  }
}

// ---------------------------------------------------------------------------
// Preps (read bf16 qkv/kv): emit bf16 K [g][key][64], bf16 Vt [g][64][key],
// and Q (self: roped+0.125-prescaled bf16; s2s: raw f32; cross: K prescaled).
// ---------------------------------------------------------------------------
__global__ __launch_bounds__(256) void prep_self_k(
    const u16* __restrict__ qkvU, const float* __restrict__ t_enc,
    const float* __restrict__ s_enc,
    u16* __restrict__ Qb, u16* __restrict__ Kb, u16* __restrict__ Vt)
{
  __shared__ u16 vs[64][66];
  const int g = blockIdx.x >> 3, i0 = (blockIdx.x & 7)*64;
  const int h = g & 3, bn = g >> 2;                 // bn 0..23 (t:0-11, s:12-23)
  const float* enc = (bn < 12) ? t_enc : s_enc;
  const int n = (bn < 12 ? bn : bn - 12) % kN;
  const int c = threadIdx.x & 63, t4 = threadIdx.x >> 6;
  const float sgn = (c & 1) ? 1.f : -1.f;
  #pragma unroll 4
  for (int rr = 0; rr < 16; ++rr) {
    const int il = rr*4 + t4, i = i0 + il;
    const u16* base = qkvU + ((size_t)bn*kM + i)*768 + h*192;
    const float q = b2f(base[c*3]), k = b2f(base[c*3+1]);
    const float qp = b2f(base[(c^1)*3]), kp = b2f(base[(c^1)*3+1]);
    const size_t eo = ((size_t)(n*kM + i))*kHD + c;
    const float e0 = enc[eo], e1 = enc[kEncSlab + eo];
    Qb[((size_t)g*kM + i)*kHD + c] = f2b((q*e0 + sgn*qp*e1)*0.125f);
    Kb[((size_t)g*kM + i)*kHD + c] = f2b(k*e0 + sgn*kp*e1);
    vs[il][c] = base[c*3+2];
  }
  __syncthreads();
  #pragma unroll 4
  for (int rr = 0; rr < 16; ++rr) {
    const int cc = rr*4 + t4;
    Vt[((size_t)g*kHD + cc)*kM + i0 + c] = vs[c][cc];
  }
}

__global__ __launch_bounds__(256) void prep_s2s_k(
    const u16* __restrict__ qkvU, const float* __restrict__ kenc,
    float* __restrict__ Qs, u16* __restrict__ Kb, u16* __restrict__ Vt)
{
  __shared__ u16 vs[64][66];
  const int g = blockIdx.x >> 3, i0 = (blockIdx.x & 7)*64;   // g = bh*6+view
  const int view = g % kN, bh = g / kN;
  const int h = bh & 3, b = bh >> 2;
  const int c = threadIdx.x & 63, t4 = threadIdx.x >> 6;
  const float sgn = (c & 1) ? 1.f : -1.f;
  #pragma unroll 4
  for (int rr = 0; rr < 16; ++rr) {
    const int il = rr*4 + t4, i = i0 + il;
    const u16* base = qkvU + ((size_t)(kRowsH + (b*kN+view)*kM + i))*768 + h*192;
    const float k = b2f(base[c*3+1]), kp = b2f(base[(c^1)*3+1]);
    const size_t eo = ((size_t)(view*kM + i))*kHD + c;
    const float e0 = kenc[eo], e1 = kenc[kEncSlab + eo];
    Qs[((size_t)g*kM + i)*kHD + c] = b2f(base[c*3]);
    Kb[((size_t)g*kM + i)*kHD + c] = f2b(k*e0 + sgn*kp*e1);
    vs[il][c] = base[c*3+2];
  }
  __syncthreads();
  #pragma unroll 4
  for (int rr = 0; rr < 16; ++rr) {
    const int cc = rr*4 + t4;
    Vt[((size_t)g*kHD + cc)*kM + i0 + c] = vs[c][cc];
  }
}

__global__ __launch_bounds__(256) void prep_cross_k(
    const u16* __restrict__ kvU, u16* __restrict__ Kb, u16* __restrict__ Vt)
{
  __shared__ u16 vs[64][66];
  const int g = blockIdx.x >> 3, i0 = (blockIdx.x & 7)*64;
  const int h = g & 3, bn = g >> 2;
  const int c = threadIdx.x & 63, t4 = threadIdx.x >> 6;
  #pragma unroll 4
  for (int rr = 0; rr < 16; ++rr) {
    const int il = rr*4 + t4, i = i0 + il;
    const u16* base = kvU + ((size_t)bn*kM + i)*512 + h*128;
    Kb[((size_t)g*kM + i)*kHD + c] = f2b(b2f(base[c*2]) * 0.125f);
    vs[il][c] = base[c*2+1];
  }
  __syncthreads();
  #pragma unroll 4
  for (int rr = 0; rr < 16; ++rr) {
    const int cc = rr*4 + t4;
    Vt[((size_t)g*kHD + cc)*kM + i0 + c] = vs[c][cc];
  }
}

// ---------------------------------------------------------------------------
// MFMA attention core: one wave, 16 q-rows, 512 keys, online softmax.
// Scores are pre-scaled via Q (self/s2s) or K (cross).
// ---------------------------------------------------------------------------
__device__ __forceinline__ void attn_core(
    const u16* __restrict__ Kg, const u16* __restrict__ Vg,
    s16x8 qf0, s16x8 qf1, u16* __restrict__ pw,   // pw: wave's [16][40] u16
    int qr, int hi, f32x4 acc[4], float& m, float& l)
{
  const int sq = qr & 3;
  for (int kc = 0; kc < 16; ++kc) {
    const int k0 = kc*32;
    f32x4 st[2];
    #pragma unroll
    for (int t = 0; t < 2; ++t) {
      const u16* kp = Kg + ((size_t)(k0 + t*16 + qr))*kHD + hi*8;
      s16x8 a0 = *(const s16x8*)(kp);
      s16x8 a1 = *(const s16x8*)(kp + 32);
      f32x4 z = {0.f, 0.f, 0.f, 0.f};
      z = __builtin_amdgcn_mfma_f32_16x16x32_bf16(a0, qf0, z, 0, 0, 0);
      z = __builtin_amdgcn_mfma_f32_16x16x32_bf16(a1, qf1, z, 0, 0, 0);
      st[t] = z;
    }
    float mloc = fmaxf(fmaxf(fmaxf(st[0][0], st[0][1]), fmaxf(st[0][2], st[0][3])),
                       fmaxf(fmaxf(st[1][0], st[1][1]), fmaxf(st[1][2], st[1][3])));
    mloc = fmaxf(mloc, __shfl_xor(mloc, 16));
    mloc = fmaxf(mloc, __shfl_xor(mloc, 32));
    const float mn = fmaxf(m, mloc);
    const float r = exp2f((m - mn)*kL2E);
    m = mn;
    float p[8], ls = 0.f;
    #pragma unroll
    for (int t = 0; t < 2; ++t)
      #pragma unroll
      for (int j = 0; j < 4; ++j) {
        const float pv = exp2f((st[t][j] - mn)*kL2E);
        p[t*4+j] = pv; ls += pv;
      }
    l = l*r + ls;
    const float rr0 = __shfl(r, hi*4+0), rr1 = __shfl(r, hi*4+1);
    const float rr2 = __shfl(r, hi*4+2), rr3 = __shfl(r, hi*4+3);
    #pragma unroll
    for (int db = 0; db < 4; ++db) {
      acc[db][0] *= rr0; acc[db][1] *= rr1; acc[db][2] *= rr2; acc[db][3] *= rr3;
    }
    union { u16 u[8]; uint2 d[2]; } pb;
    #pragma unroll
    for (int j = 0; j < 8; ++j) pb.u[j] = f2b(p[j]);
    *(uint2*)&pw[qr*40 + (((hi>>1)    ) ^ sq)*8 + (hi&1)*4] = pb.d[0];
    *(uint2*)&pw[qr*40 + ((2+(hi>>1)) ^ sq)*8 + (hi&1)*4] = pb.d[1];
    const s16x8 pa = *(const s16x8*)&pw[qr*40 + (hi ^ sq)*8];
    #pragma unroll
    for (int db = 0; db < 4; ++db) {
      const u16* vp = Vg + ((size_t)(db*16 + qr))*kM + k0 + hi*8;
      const s16x8 vf = *(const s16x8*)(vp);
      acc[db] = __builtin_amdgcn_mfma_f32_16x16x32_bf16(pa, vf, acc[db], 0, 0, 0);
    }
  }
}

// self (CROSSQ=0: Qb [96g][512][64] prescaled) / cross (CROSSQ=1: Qb=[12288][256] raw)
template<int CROSSQ>
__global__ __launch_bounds__(256) void attn_mm_k(
    const u16* __restrict__ Qb, const u16* __restrict__ Kb,
    const u16* __restrict__ Vt, u16* __restrict__ ctx)
{
  __shared__ u16 p_lds[4][16][40];
  const int w = threadIdx.x >> 6, lane = threadIdx.x & 63;
  const int bij = (blockIdx.x & 7)*96 + (blockIdx.x >> 3);   // XCD-bijective, 768
  const int g = bij >> 3, qblk = bij & 7;
  const int h = g & 3, bn = g >> 2;
  const int q0 = qblk*64 + w*16;
  const int qr = lane & 15, hi = lane >> 4;

  s16x8 qf0, qf1;
  if (CROSSQ) {
    const u16* qp = Qb + ((size_t)(bn*kM + q0 + qr))*kD + h*kHD + hi*8;
    qf0 = *(const s16x8*)(qp); qf1 = *(const s16x8*)(qp + 32);
  } else {
    const u16* qp = Qb + ((size_t)g*kM + q0 + qr)*kHD + hi*8;
    qf0 = *(const s16x8*)(qp); qf1 = *(const s16x8*)(qp + 32);
  }

  const u16* Kg = Kb + (size_t)g*kM*kHD;
  const u16* Vg = Vt + (size_t)g*kHD*kM;
  f32x4 acc[4] = {};
  float m = -1e30f, l = 0.f;
  attn_core(Kg, Vg, qf0, qf1, &p_lds[w][0][0], qr, hi, acc, m, l);

  l += __shfl_xor(l, 16); l += __shfl_xor(l, 32);
  const float li = 1.f/l;
  const float l0 = __shfl(li, hi*4+0), l1 = __shfl(li, hi*4+1);
  const float l2 = __shfl(li, hi*4+2), l3 = __shfl(li, hi*4+3);
  #pragma unroll
  for (int db = 0; db < 4; ++db) {
    const size_t base = ((size_t)(bn*kM + q0 + hi*4))*kD + h*kHD + db*16 + qr;
    ctx[base + 0*kD] = f2b(acc[db][0]*l0);
    ctx[base + 1*kD] = f2b(acc[db][1]*l1);
    ctx[base + 2*kD] = f2b(acc[db][2]*l2);
    ctx[base + 3*kD] = f2b(acc[db][3]*l3);
  }
}

__device__ __forceinline__ void rope4(const f32x4 x, const f32x4 e0, const f32x4 e1, float o[4])
{
  o[0] = x[0]*e0[0] - x[1]*e1[0];
  o[1] = x[1]*e0[1] + x[0]*e1[1];
  o[2] = x[2]*e0[2] - x[3]*e1[2];
  o[3] = x[3]*e0[3] + x[2]*e1[3];
}

// s2s: block = (bh, col, qblk, split); split0 = pairs {0,1,2}, split1 = {3,4}.
// Writes 0.2-scaled normalized partials (f32) to ctx2[split].
__global__ __launch_bounds__(256) void attn_s2s_k(
    const float* __restrict__ Qraw, const u16* __restrict__ Kb,
    const u16* __restrict__ Vt, const float* __restrict__ qenc,
    float* __restrict__ ctx2)
{
  __shared__ u16 p_lds[4][16][40];
  const int w = threadIdx.x >> 6, lane = threadIdx.x & 63;
  const int bij = (blockIdx.x & 7)*96 + (blockIdx.x >> 3);   // 768; chunk == bh
  const int bh = bij / 96;
  const int rest = bij % 96;
  const int split = rest & 1, qblk = (rest >> 1) & 7, col = rest >> 4;
  const int q0 = qblk*64 + w*16;
  const int qr = lane & 15, hi = lane >> 4;
  f32x4 macc[4] = {};
  const int r5lo = split ? 3 : 0, r5hi = split ? 5 : 3;

  for (int r5 = r5lo; r5 < r5hi; ++r5) {
    const int e  = r5*6 + col;
    const int iv = e/5;
    const int j0 = e%5;
    const int jv = j0 + (j0 >= iv ? 1 : 0);
    s16x8 qf0, qf1;
    {
      const float* qp = Qraw + ((size_t)(bh*kN + jv)*kM + q0 + qr)*kHD + hi*8;
      const float* ep = qenc + ((size_t)(iv*kN + jv))*kHD + hi*8;
      union { u16 u[8]; s16x8 v; } A, B;
      float o[4];
      rope4(*(const f32x4*)(qp),   *(const f32x4*)(ep),   *(const f32x4*)(ep+kQEncSlab), o);
      #pragma unroll
      for (int j = 0; j < 4; ++j) A.u[j] = f2b(o[j]*0.125f);
      rope4(*(const f32x4*)(qp+4), *(const f32x4*)(ep+4), *(const f32x4*)(ep+kQEncSlab+4), o);
      #pragma unroll
      for (int j = 0; j < 4; ++j) A.u[4+j] = f2b(o[j]*0.125f);
      rope4(*(const f32x4*)(qp+32), *(const f32x4*)(ep+32), *(const f32x4*)(ep+kQEncSlab+32), o);
      #pragma unroll
      for (int j = 0; j < 4; ++j) B.u[j] = f2b(o[j]*0.125f);
      rope4(*(const f32x4*)(qp+36), *(const f32x4*)(ep+36), *(const f32x4*)(ep+kQEncSlab+36), o);
      #pragma unroll
      for (int j = 0; j < 4; ++j) B.u[4+j] = f2b(o[j]*0.125f);
      qf0 = A.v; qf1 = B.v;
    }
    const int g2 = bh*kN + iv;
    const u16* Kg = Kb + (size_t)g2*kM*kHD;
    const u16* Vg = Vt + (size_t)g2*kHD*kM;
    f32x4 acc[4] = {};
    float m = -1e30f, l = 0.f;
    attn_core(Kg, Vg, qf0, qf1, &p_lds[w][0][0], qr, hi, acc, m, l);
    l += __shfl_xor(l, 16); l += __shfl_xor(l, 32);
    const float li = 0.2f/l;
    const float l0 = __shfl(li, hi*4+0), l1 = __shfl(li, hi*4+1);
    const float l2 = __shfl(li, hi*4+2), l3 = __shfl(li, hi*4+3);
    #pragma unroll
    for (int db = 0; db < 4; ++db) {
      macc[db][0] += acc[db][0]*l0;
      macc[db][1] += acc[db][1]*l1;
      macc[db][2] += acc[db][2]*l2;
      macc[db][3] += acc[db][3]*l3;
    }
  }
  const int b = bh >> 2, h = bh & 3;
  float* outp = ctx2 + (size_t)split*kTOK;
  #pragma unroll
  for (int db = 0; db < 4; ++db) {
    const size_t base = ((size_t)((b*kN + col)*kM + q0 + hi*4))*kD + h*kHD + db*16 + qr;
    outp[base + 0*kD] = macc[db][0];
    outp[base + 1*kD] = macc[db][1];
    outp[base + 2*kD] = macc[db][2];
    outp[base + 3*kD] = macc[db][3];
  }
}

__global__ __launch_bounds__(256) void sum2_k(const float* __restrict__ c2,
                                              u16* __restrict__ outU)
{
  const size_t i4 = ((size_t)blockIdx.x*256 + threadIdx.x)*4;
  f32x4 a = *(const f32x4*)(c2 + i4);
  f32x4 b = *(const f32x4*)(c2 + kTOK + i4);
  union { u16 u[4]; uint2 d; } o;
  #pragma unroll
  for (int j = 0; j < 4; ++j) o.u[j] = f2b(a[j] + b[j]);
  *(uint2*)(outU + i4) = o.d;
}

// t2t attention: wave per (b,h,nq,m) — 24576 waves.
__global__ __launch_bounds__(256) void attn_t2t_k(
    const u16* __restrict__ qkvU, u16* __restrict__ ctxU)
{
  const int wid = blockIdx.x*4 + (threadIdx.x >> 6);
  const int lane = threadIdx.x & 63;
  const int m = wid & 511;
  const int t = wid >> 9;
  const int nq = t % kN;
  const int bh = t / kN;
  const int h = bh & 3, b = bh >> 2;
  const u16* pb[kN];
  #pragma unroll
  for (int nk = 0; nk < kN; ++nk)
    pb[nk] = qkvU + ((size_t)(b*kN+nk)*kM + m)*768 + h*192;
  const float qc = b2f(pb[nq][lane*3]);
  float sim[kN];
  #pragma unroll
  for (int nk = 0; nk < kN; ++nk)
    sim[nk] = wred_sum(qc * b2f(pb[nk][lane*3+1])) * 0.125f;
  float mx = sim[0];
  #pragma unroll
  for (int nk = 1; nk < kN; ++nk) mx = fmaxf(mx, sim[nk]);
  float p[kN], s = 0.f;
  #pragma unroll
  for (int nk = 0; nk < kN; ++nk) { p[nk] = expf(sim[nk]-mx); s += p[nk]; }
  const float inv = 1.f/s;
  float o = 0.f;
  #pragma unroll
  for (int nk = 0; nk < kN; ++nk) o = fmaf(p[nk], b2f(pb[nk][lane*3+2]), o);
  ctxU[((size_t)(b*kN+nq)*kM + m)*kD + h*kHD + lane] = f2b(o*inv);
}

// LayerNorm(512) + exact GELU: reads f32, writes bf16 (separate buffer).
__global__ __launch_bounds__(256) void lngelu_k(
    const float* __restrict__ x, u16* __restrict__ y,
    const float* __restrict__ g0, const float* __restrict__ b0,
    const float* __restrict__ g1, const float* __restrict__ b1, int Mh)
{
  const int row = blockIdx.x;
  const int tid = threadIdx.x;
  const float* g = (row < Mh) ? g0 : g1;
  const float* bb = (row < Mh) ? b0 : b1;
  const float* xr = x + (size_t)row*512;
  const float v0 = xr[tid], v1 = xr[tid+256];
  const int w = tid >> 6, lane = tid & 63;
  __shared__ float red[2][4];
  const float s1 = wred_sum(v0+v1);
  const float s2 = wred_sum(v0*v0+v1*v1);
  if (lane == 0){ red[0][w]=s1; red[1][w]=s2; }
  __syncthreads();
  const float mean = (red[0][0]+red[0][1]+red[0][2]+red[0][3]) * (1.f/512.f);
  const float ms   = (red[1][0]+red[1][1]+red[1][2]+red[1][3]) * (1.f/512.f);
  const float rs = rsqrtf(ms - mean*mean + 1e-5f);
  const float y0 = (v0-mean)*rs*g[tid]     + bb[tid];
  const float y1 = (v1-mean)*rs*g[tid+256] + bb[tid+256];
  y[(size_t)row*512 + tid]     = f2b(0.5f*y0*(1.f+erff(y0*0.70710678118654752f)));
  y[(size_t)row*512 + tid+256] = f2b(0.5f*y1*(1.f+erff(y1*0.70710678118654752f)));
}

__global__ void conf_dot_k(const float* __restrict__ tmp, const float* __restrict__ w2,
                           const float* __restrict__ b2, float* __restrict__ out)
{
  const int w = threadIdx.x >> 6, lane = threadIdx.x & 63;
  const int row = blockIdx.x*4 + w;
  const float* t = tmp + (size_t)row*kD;
  float s = 0.f;
  #pragma unroll
  for (int j=0;j<4;++j) s = fmaf(t[lane+j*64], w2[lane+j*64], s);
  s = wred_sum(s);
  if (lane == 0) out[row] = s + b2[0];
}

// ---------------------------------------------------------------------------
extern "C" void kernel_launch(void* const* d_in, const int* in_sizes, int n_in,
                              void* d_out, int out_size, void* d_ws, size_t ws_size,
                              hipStream_t stream)
{
  auto F = [&](int i){ return (const float*)d_in[i]; };
  const float* t_desc = F(0);
  const float* s_desc = F(1);
  const float* t_enc  = F(2);
  const float* s_enc  = F(3);
  const float* q_enc  = F(4);
  const float* k_enc  = F(5);

  // ---- workspace map (74.6 MB total) ----
  char* base = (char*)d_ws;
  float* xts = (float*)base;                     // 12288x256 f32 (xt|xs)
  float* xt = xts;
  float* xs = xts + kTOK;
  char* R1  = base + 2*kTOK*sizeof(float);       // 25.17 MB multi-use
  char* CTX = R1 + 4*kTOK*sizeof(float);         // 6.29 MB
  char* MSG = CTX + 2*kTOK*sizeof(u16);          // 6.29 MB
  u16* Qb16 = (u16*)(MSG + kTOK*sizeof(float));  // 96x512x64
  u16* Kb16 = Qb16 + 2*kTOK;
  u16* Vt16 = Kb16 + 2*kTOK;
  u16* wsW  = Vt16 + 2*kTOK;
  // aliases
  u16*   qkvU  = (u16*)R1;                       // 12288x768
  u16*   qU    = (u16*)R1;                       // 12288x256 (cross q)
  u16*   kvU   = (u16*)R1 + (size_t)kRows*kD;    // 12288x512 (cross kv)
  float* hbuf  = (float*)R1;                     // 12288x512 f32
  float* ctx2  = (float*)R1;                     // 2 x 6144x256 f32 (s2s partials)
  u16*   ctxU  = (u16*)CTX;                      // 12288x256
  u16*   msgU  = (u16*)MSG;                      // 12288x256
  float* Qs2s  = (float*)MSG;                    // 48x512x64 f32
  float* confb = (float*)MSG;                    // 6144x256 f32
  u16*   yU    = (u16*)CTX;                      // 12288x512 (spans CTX+MSG)

  float* out_t2s2 = (float*)d_out;               // rows 0..12287 (t2|s2)
  float* out_conf = (float*)d_out + 2*kTOK;

  // ---- weight transpose+cast table ----
  WtTable tab;
  int nd = 0, total_tiles = 0;
  size_t woff = 0;
  const u16* wp[18];
  auto addw = [&](int idx, int K, int N){
    u16* dst = wsW + woff;
    tab.d[nd] = { F(idx), dst, K, N, (K>>5)*(N>>5) };
    total_tiles += tab.d[nd].ntiles;
    wp[nd] = dst;
    woff += (size_t)K*N;
    ++nd;
    return nd-1;
  };
  const int W_SA_QKV = addw(6, 256, 768);
  const int W_SA_OUT = addw(8, 256, 256);
  const int W_SA_F1  = addw(10, 512, 512);
  const int W_SA_F2  = addw(14, 512, 256);
  const int W_SS_QKV = addw(16, 256, 768);
  const int W_SS_OUT = addw(18, 256, 256);
  const int W_SS_F1  = addw(20, 512, 512);
  const int W_SS_F2  = addw(24, 512, 256);
  const int W_TT_QKV = addw(26, 256, 768);
  const int W_TT_OUT = addw(28, 256, 256);
  const int W_TT_F1  = addw(30, 512, 512);
  const int W_TT_F2  = addw(34, 512, 256);
  const int W_CA_Q   = addw(36, 256, 256);
  const int W_CA_KV  = addw(38, 256, 512);
  const int W_CA_OUT = addw(40, 256, 256);
  const int W_CA_F1  = addw(42, 512, 512);
  const int W_CA_F2  = addw(46, 512, 256);
  const int W_CF_1   = addw(48, 256, 256);
  wtcast_k<<<total_tiles, 256, 0, stream>>>(tab);

  // mmad launchers (dual row-segment, 12288 rows unless noted)
  auto mm_f32_to_b16 = [&](const float* a1a, const float* a1b, int wa, int wb2,
                           const float* ba, const float* bb2, u16* c, int N_, int K_){
    dim3 grid(N_/128, kRows/128);
    mmad_k<false,false,true><<<grid,256,0,stream>>>(a1a, a1b, nullptr, nullptr, K_,
        wp[wa], wp[wb2], ba, bb2, nullptr, nullptr, c, N_, K_, kRowsH, 0);
  };
  auto mm_b16_to_b16 = [&](const u16* a1a, const u16* a1b, int wa, int wb2,
                           const float* ba, const float* bb2, u16* c, int N_, int K_){
    dim3 grid(N_/128, kRows/128);
    mmad_k<true,false,true><<<grid,256,0,stream>>>(a1a, a1b, nullptr, nullptr, K_,
        wp[wa], wp[wb2], ba, bb2, nullptr, nullptr, c, N_, K_, kRowsH, 0);
  };
  auto mm_f1 = [&](const float* a1a, const float* a1b, const u16* a2a, const u16* a2b,
                   int wa, int wb2, const float* ba, const float* bb2, float* c){
    dim3 grid(512/128, kRows/128);
    mmad_k<false,true,false><<<grid,256,0,stream>>>(a1a, a1b, a2a, a2b, 256,
        wp[wa], wp[wb2], ba, bb2, nullptr, nullptr, c, 512, 512, kRowsH, 0);
  };
  auto mm_f2 = [&](const u16* a1a, const u16* a1b, int wa, int wb2,
                   const float* ba, const float* bb2,
                   const float* ra, const float* rb, float* c){
    dim3 grid(256/128, kRows/128);
    mmad_k<true,false,false><<<grid,256,0,stream>>>(a1a, a1b, nullptr, nullptr, 512,
        wp[wa], wp[wb2], ba, bb2, ra, rb, c, 256, 512, kRowsH, 0);
  };

  // ================= SELF (t || s, shared sa weights) =================
  mm_f32_to_b16(t_desc, s_desc, W_SA_QKV, W_SA_QKV, F(7), F(7), qkvU, 768, 256);
  prep_self_k<<<kGrp*8, 256, 0, stream>>>(qkvU, t_enc, s_enc, Qb16, Kb16, Vt16);
  attn_mm_k<0><<<kGrp*8, 256, 0, stream>>>(Qb16, Kb16, Vt16, ctxU);
  mm_b16_to_b16(ctxU, ctxU + kTOK, W_SA_OUT, W_SA_OUT, F(9), F(9), msgU, 256, 256);
  mm_f1(t_desc, s_desc, msgU, msgU + kTOK, W_SA_F1, W_SA_F1, F(11), F(11), hbuf);
  lngelu_k<<<kRows, 256, 0, stream>>>(hbuf, yU, F(12), F(13), F(12), F(13), kRowsH);
  mm_f2(yU, yU + (size_t)kRowsH*512, W_SA_F2, W_SA_F2, F(15), F(15), t_desc, s_desc, xts);

  // ================= TT (t) || SS (s) =================
  mm_f32_to_b16(xt, xs, W_TT_QKV, W_SS_QKV, F(27), F(17), qkvU, 768, 256);
  prep_s2s_k<<<kGrpH*8, 256, 0, stream>>>(qkvU, k_enc, Qs2s, Kb16, Vt16);
  attn_t2t_k<<<(kB*kH*kN*kM)/4, 256, 0, stream>>>(qkvU, ctxU);
  attn_s2s_k<<<kGrp*8, 256, 0, stream>>>(Qs2s, Kb16, Vt16, q_enc, ctx2);
  sum2_k<<<(int)(kTOK/1024), 256, 0, stream>>>(ctx2, ctxU + kTOK);
  mm_b16_to_b16(ctxU, ctxU + kTOK, W_TT_OUT, W_SS_OUT, F(29), F(19), msgU, 256, 256);
  mm_f1(xt, xs, msgU, msgU + kTOK, W_TT_F1, W_SS_F1, F(31), F(21), hbuf);
  lngelu_k<<<kRows, 256, 0, stream>>>(hbuf, yU, F(32), F(33), F(22), F(23), kRowsH);
  mm_f2(yU, yU + (size_t)kRowsH*512, W_TT_F2, W_SS_F2, F(35), F(25), xt, xs, xts);

  // ================= CONF (from xs post-s2s) =================
  {
    dim3 grid(2, kRowsH/128);
    mmad_k<false,false,false><<<grid,256,0,stream>>>(xs, xs, nullptr, nullptr, 256,
        wp[W_CF_1], wp[W_CF_1], F(49), F(49), nullptr, nullptr, confb, 256, 256, kRowsH, 1);
  }
  conf_dot_k<<<kRowsH/4, 256, 0, stream>>>(confb, F(50), F(51), out_conf);

  // ================= CROSS (t2: q=xt,kv=xs || s2: q=xs,kv=xt) =================
  mm_f32_to_b16(xt, xs, W_CA_Q, W_CA_Q, F(37), F(37), qU, 256, 256);
  mm_f32_to_b16(xs, xt, W_CA_KV, W_CA_KV, F(39), F(39), kvU, 512, 256);
  prep_cross_k<<<kGrp*8, 256, 0, stream>>>(kvU, Kb16, Vt16);
  attn_mm_k<1><<<kGrp*8, 256, 0, stream>>>(qU, Kb16, Vt16, ctxU);
  mm_b16_to_b16(ctxU, ctxU + kTOK, W_CA_OUT, W_CA_OUT, F(41), F(41), msgU, 256, 256);
  mm_f1(xt, xs, msgU, msgU + kTOK, W_CA_F1, W_CA_F1, F(43), F(43), hbuf);
  lngelu_k<<<kRows, 256, 0, stream>>>(hbuf, yU, F(44), F(45), F(44), F(45), kRowsH);
  mm_f2(yU, yU + (size_t)kRowsH*512, W_CA_F2, W_CA_F2, F(47), F(47), xt, xs, out_t2s2);
}

// Round 6
// 580.503 us; speedup vs baseline: 3.6758x; 1.0249x over previous
//
#include <hip/hip_runtime.h>
#include <hip/hip_bf16.h>
#include <math.h>

// Problem constants
constexpr int kD   = 256;   // model dim
constexpr int kH   = 4;     // heads
constexpr int kHD  = 64;    // head dim
constexpr int kB   = 2;
constexpr int kN   = 6;     // views
constexpr int kM   = 512;   // keypoints (M == NS)
constexpr int kRowsH = kB*kN*kM;          // 6144 rows per half (t or s)
constexpr int kRows  = 2*kRowsH;          // 12288 merged rows
constexpr int kGrpH  = kB*kN*kH;          // 48 attention groups per half
constexpr int kGrp   = 2*kGrpH;           // 96 merged groups
constexpr size_t kTOK = (size_t)kRowsH*kD;        // 1,572,864
constexpr size_t kEncSlab = (size_t)kN*kM*kHD;    // 196608
constexpr size_t kQEncSlab = (size_t)kN*kN*kHD;   // 2304
constexpr float kL2E = 1.4426950408889634f;

typedef unsigned short u16;
typedef __attribute__((ext_vector_type(8))) short s16x8;
typedef __attribute__((ext_vector_type(4))) float f32x4;

__device__ __forceinline__ float wred_sum(float v){
  #pragma unroll
  for (int m=32;m>0;m>>=1) v += __shfl_xor(v, m, 64);
  return v;
}
__device__ __forceinline__ u16 f2b(float x){
  union { float f; unsigned u; } a; a.f = x;
  unsigned r = a.u + 0x7fffu + ((a.u >> 16) & 1u);
  return (u16)(r >> 16);
}
__device__ __forceinline__ float b2f(u16 x){
  union { unsigned u; float f; } a; a.u = ((unsigned)x) << 16;
  return a.f;
}
// pack two f32 -> u32 of {lo16=bf16(lo), hi16=bf16(hi)} via HIP intrinsic
__device__ __forceinline__ unsigned pk2(float lo, float hi){
  union { __hip_bfloat162 h2; unsigned u; } c;
  c.h2 = __float22bfloat162_rn(make_float2(lo, hi));
  return c.u;
}

// ---------------------------------------------------------------------------
// Weight transpose+cast: W[K][N] f32 -> Wt[N][K] bf16. Batched over matrices.
// ---------------------------------------------------------------------------
struct WtDesc { const float* W; u16* Wt; int K; int N; int ntiles; };
struct WtTable { WtDesc d[18]; };

__global__ __launch_bounds__(256) void wtcast_k(WtTable tab)
{
  int t = blockIdx.x, mi = 0;
  while (t >= tab.d[mi].ntiles) { t -= tab.d[mi].ntiles; ++mi; }
  const float* W = tab.d[mi].W;
  u16* Wt = tab.d[mi].Wt;
  const int K = tab.d[mi].K, N = tab.d[mi].N;
  const int ntn = N >> 5;
  const int n0 = (t % ntn) * 32, k0 = (t / ntn) * 32;
  __shared__ float tile[32][33];
  const int tx = threadIdx.x & 31, ty = threadIdx.x >> 5;
  #pragma unroll
  for (int i = 0; i < 32; i += 8)
    tile[ty+i][tx] = W[(size_t)(k0+ty+i)*N + n0+tx];
  __syncthreads();
  #pragma unroll
  for (int i = 0; i < 32; i += 8)
    Wt[(size_t)(n0+ty+i)*K + k0+tx] = f2b(tile[tx][ty+i]);
}

// ---------------------------------------------------------------------------
// bf16 MFMA GEMM, dual row-segment (rows<Mh use seg a, else seg b).
// ---------------------------------------------------------------------------
template<bool A1B, bool A2B, bool CB>
__global__ __launch_bounds__(256) void mmad_k(
    const void* __restrict__ A1a, const void* __restrict__ A1b,
    const void* __restrict__ A2a, const void* __restrict__ A2b, int K1,
    const u16* __restrict__ Wa, const u16* __restrict__ Wb,
    const float* __restrict__ bia, const float* __restrict__ bib,
    const float* __restrict__ Ra, const float* __restrict__ Rb,
    void* __restrict__ Cp, int N, int K, int Mh, int doRelu)
{
  __shared__ u16 As[128*32];
  __shared__ u16 Bs[128*32];
  const int tid = threadIdx.x;
  const int lane = tid & 63, w = tid >> 6;
  const int row0 = blockIdx.y*128, col0 = blockIdx.x*128;
  const bool sec = (row0 >= Mh);
  const int lr0 = sec ? row0 - Mh : row0;
  const void* A1 = sec ? A1b : A1a;
  const void* A2 = sec ? A2b : A2a;
  const u16* Wt  = sec ? Wb : Wa;
  const float* bias = sec ? bib : bia;
  const float* R = sec ? Rb : Ra;
  const int wr = (w >> 1)*64, wc = (w & 1)*64;
  const int ar = tid >> 1, ah = tid & 1;
  const int K2 = K - K1;
  f32x4 acc[4][4] = {};

  for (int kt = 0; kt < K; kt += 32) {
    const int kk = kt + ah*16;
    union { u16 u[16]; s16x8 v[2]; } tmp;
    if (kk < K1) {
      if constexpr (A1B) {
        const u16* ap = (const u16*)A1 + (size_t)(lr0+ar)*K1 + kk;
        tmp.v[0] = *(const s16x8*)ap; tmp.v[1] = *(const s16x8*)(ap+8);
      } else {
        const float* ap = (const float*)A1 + (size_t)(lr0+ar)*K1 + kk;
        #pragma unroll
        for (int i = 0; i < 16; i += 4) {
          f32x4 v4 = *(const f32x4*)(ap + i);
          tmp.u[i+0]=f2b(v4.x); tmp.u[i+1]=f2b(v4.y); tmp.u[i+2]=f2b(v4.z); tmp.u[i+3]=f2b(v4.w);
        }
      }
    } else {
      if constexpr (A2B) {
        const u16* ap = (const u16*)A2 + (size_t)(lr0+ar)*K2 + (kk - K1);
        tmp.v[0] = *(const s16x8*)ap; tmp.v[1] = *(const s16x8*)(ap+8);
      } else {
        const float* ap = (const float*)A2 + (size_t)(lr0+ar)*K2 + (kk - K1);
        #pragma unroll
        for (int i = 0; i < 16; i += 4) {
          f32x4 v4 = *(const f32x4*)(ap + i);
          tmp.u[i+0]=f2b(v4.x); tmp.u[i+1]=f2b(v4.y); tmp.u[i+2]=f2b(v4.z); tmp.u[i+3]=f2b(v4.w);
        }
      }
    }
    const int sw = (ar >> 1) & 3;
    *(s16x8*)(&As[ar*32 + ((ah*2+0)^sw)*8]) = tmp.v[0];
    *(s16x8*)(&As[ar*32 + ((ah*2+1)^sw)*8]) = tmp.v[1];
    {
      const u16* bp = Wt + (size_t)(col0+ar)*K + kt + ah*16;
      s16x8 b0 = *(const s16x8*)(bp);
      s16x8 b1 = *(const s16x8*)(bp + 8);
      *(s16x8*)(&Bs[ar*32 + ((ah*2+0)^sw)*8]) = b0;
      *(s16x8*)(&Bs[ar*32 + ((ah*2+1)^sw)*8]) = b1;
    }
    __syncthreads();
    s16x8 af[4], bfv[4];
    #pragma unroll
    for (int fm = 0; fm < 4; ++fm) {
      const int r = wr + fm*16 + (lane & 15);
      const int g = (lane >> 4) ^ ((r >> 1) & 3);
      af[fm] = *(const s16x8*)(&As[r*32 + g*8]);
    }
    #pragma unroll
    for (int fn = 0; fn < 4; ++fn) {
      const int c = wc + fn*16 + (lane & 15);
      const int g = (lane >> 4) ^ ((c >> 1) & 3);
      bfv[fn] = *(const s16x8*)(&Bs[c*32 + g*8]);
    }
    #pragma unroll
    for (int fm = 0; fm < 4; ++fm)
      #pragma unroll
      for (int fn = 0; fn < 4; ++fn)
        acc[fm][fn] = __builtin_amdgcn_mfma_f32_16x16x32_bf16(af[fm], bfv[fn], acc[fm][fn], 0, 0, 0);
    __syncthreads();
  }

  #pragma unroll
  for (int fm = 0; fm < 4; ++fm) {
    const int ro = wr + fm*16 + (lane >> 4)*4;
    #pragma unroll
    for (int fn = 0; fn < 4; ++fn) {
      const int cc = col0 + wc + fn*16 + (lane & 15);
      const float bv = bias[cc];
      #pragma unroll
      for (int j = 0; j < 4; ++j) {
        float v = acc[fm][fn][j] + bv;
        if (R) v += R[(size_t)(lr0 + ro + j)*N + cc];
        if (doRelu) v = fmaxf(v, 0.f);
        const size_t idx = (size_t)(row0 + ro + j)*N + cc;
        if constexpr (CB) ((u16*)Cp)[idx] = f2b(v);
        else              ((float*)Cp)[idx] = v;
      }
    }
  }
}

// ---------------------------------------------------------------------------
// Preps (read bf16 qkv/kv): emit bf16 K [g][key][64], bf16 Vt [g][64][key],
// and Q (self: roped+0.125-prescaled bf16; s2s: raw f32; cross: K prescaled).
// ---------------------------------------------------------------------------
__global__ __launch_bounds__(256) void prep_self_k(
    const u16* __restrict__ qkvU, const float* __restrict__ t_enc,
    const float* __restrict__ s_enc,
    u16* __restrict__ Qb, u16* __restrict__ Kb, u16* __restrict__ Vt)
{
  __shared__ u16 vs[64][66];
  const int g = blockIdx.x >> 3, i0 = (blockIdx.x & 7)*64;
  const int h = g & 3, bn = g >> 2;                 // bn 0..23 (t:0-11, s:12-23)
  const float* enc = (bn < 12) ? t_enc : s_enc;
  const int n = (bn < 12 ? bn : bn - 12) % kN;
  const int c = threadIdx.x & 63, t4 = threadIdx.x >> 6;
  const float sgn = (c & 1) ? 1.f : -1.f;
  #pragma unroll 4
  for (int rr = 0; rr < 16; ++rr) {
    const int il = rr*4 + t4, i = i0 + il;
    const u16* base = qkvU + ((size_t)bn*kM + i)*768 + h*192;
    const float q = b2f(base[c*3]), k = b2f(base[c*3+1]);
    const float qp = b2f(base[(c^1)*3]), kp = b2f(base[(c^1)*3+1]);
    const size_t eo = ((size_t)(n*kM + i))*kHD + c;
    const float e0 = enc[eo], e1 = enc[kEncSlab + eo];
    Qb[((size_t)g*kM + i)*kHD + c] = f2b((q*e0 + sgn*qp*e1)*0.125f);
    Kb[((size_t)g*kM + i)*kHD + c] = f2b(k*e0 + sgn*kp*e1);
    vs[il][c] = base[c*3+2];
  }
  __syncthreads();
  #pragma unroll 4
  for (int rr = 0; rr < 16; ++rr) {
    const int cc = rr*4 + t4;
    Vt[((size_t)g*kHD + cc)*kM + i0 + c] = vs[c][cc];
  }
}

__global__ __launch_bounds__(256) void prep_s2s_k(
    const u16* __restrict__ qkvU, const float* __restrict__ kenc,
    float* __restrict__ Qs, u16* __restrict__ Kb, u16* __restrict__ Vt)
{
  __shared__ u16 vs[64][66];
  const int g = blockIdx.x >> 3, i0 = (blockIdx.x & 7)*64;   // g = bh*6+view
  const int view = g % kN, bh = g / kN;
  const int h = bh & 3, b = bh >> 2;
  const int c = threadIdx.x & 63, t4 = threadIdx.x >> 6;
  const float sgn = (c & 1) ? 1.f : -1.f;
  #pragma unroll 4
  for (int rr = 0; rr < 16; ++rr) {
    const int il = rr*4 + t4, i = i0 + il;
    const u16* base = qkvU + ((size_t)(kRowsH + (b*kN+view)*kM + i))*768 + h*192;
    const float k = b2f(base[c*3+1]), kp = b2f(base[(c^1)*3+1]);
    const size_t eo = ((size_t)(view*kM + i))*kHD + c;
    const float e0 = kenc[eo], e1 = kenc[kEncSlab + eo];
    Qs[((size_t)g*kM + i)*kHD + c] = b2f(base[c*3]);
    Kb[((size_t)g*kM + i)*kHD + c] = f2b(k*e0 + sgn*kp*e1);
    vs[il][c] = base[c*3+2];
  }
  __syncthreads();
  #pragma unroll 4
  for (int rr = 0; rr < 16; ++rr) {
    const int cc = rr*4 + t4;
    Vt[((size_t)g*kHD + cc)*kM + i0 + c] = vs[c][cc];
  }
}

__global__ __launch_bounds__(256) void prep_cross_k(
    const u16* __restrict__ kvU, u16* __restrict__ Kb, u16* __restrict__ Vt)
{
  __shared__ u16 vs[64][66];
  const int g = blockIdx.x >> 3, i0 = (blockIdx.x & 7)*64;
  const int h = g & 3, bn = g >> 2;
  const int c = threadIdx.x & 63, t4 = threadIdx.x >> 6;
  #pragma unroll 4
  for (int rr = 0; rr < 16; ++rr) {
    const int il = rr*4 + t4, i = i0 + il;
    const u16* base = kvU + ((size_t)bn*kM + i)*512 + h*128;
    Kb[((size_t)g*kM + i)*kHD + c] = f2b(b2f(base[c*2]) * 0.125f);
    vs[il][c] = base[c*2+1];
  }
  __syncthreads();
  #pragma unroll 4
  for (int rr = 0; rr < 16; ++rr) {
    const int cc = rr*4 + t4;
    Vt[((size_t)g*kHD + cc)*kM + i0 + c] = vs[c][cc];
  }
}

// ---------------------------------------------------------------------------
// MFMA attention core: one wave, 16 q-rows, 512 keys, online softmax with
// defer-max (THR=8) and in-register P redistribution via shfl_xor(32/16).
// QK^T (S^T: col=q=lane&15, row=key) puts, in lane (qr,hi), keys
// t*16+hi*4+{0..3} of q-row qr in st[t][0..3]. Packed words:
//   c00=keys(t0,hi*4+{0,1}) c01=(t0,+{2,3}) c10=(t1,+{0,1}) c11=(t1,+{2,3}).
// PV A-fragment needs lane (qr,hi_d) to hold keys 8*hi_d+{0..7} as 4 words.
// Derivation: word s of dst hi_d comes from src hi_s=2*(hi_d&1)+(s>=2),
// register c[hi_d>>1][s&1]. Realized as:
//   E=[c00.lo,c10.lo] F=[c00.hi,c10.hi] G=[c01.lo,c11.lo] H=[c01.hi,c11.hi]
//   w0 = subhi ? F^16 : E ; w1 = subhi ? H^16 : G
//   w2 = subhi ? F : E^16 ; w3 = subhi ? H : G^16   (subhi = hi&1)
// (verified at lanes 0,16,32,48 for slots 0-3)
// ---------------------------------------------------------------------------
__device__ __forceinline__ void attn_core(
    const u16* __restrict__ Kg, const u16* __restrict__ Vg,
    s16x8 qf0, s16x8 qf1, int qr, int hi, f32x4 acc[4], float& m, float& l)
{
  const bool subhi = (hi & 1);
  const bool up = (hi >= 2);
  for (int kc = 0; kc < 16; ++kc) {
    const int k0 = kc*32;
    f32x4 st[2];
    #pragma unroll
    for (int t = 0; t < 2; ++t) {
      const u16* kp = Kg + ((size_t)(k0 + t*16 + qr))*kHD + hi*8;
      s16x8 a0 = *(const s16x8*)(kp);
      s16x8 a1 = *(const s16x8*)(kp + 32);
      f32x4 z = {0.f, 0.f, 0.f, 0.f};
      z = __builtin_amdgcn_mfma_f32_16x16x32_bf16(a0, qf0, z, 0, 0, 0);
      z = __builtin_amdgcn_mfma_f32_16x16x32_bf16(a1, qf1, z, 0, 0, 0);
      st[t] = z;
    }
    float mloc = fmaxf(fmaxf(fmaxf(st[0][0], st[0][1]), fmaxf(st[0][2], st[0][3])),
                       fmaxf(fmaxf(st[1][0], st[1][1]), fmaxf(st[1][2], st[1][3])));
    mloc = fmaxf(mloc, __shfl_xor(mloc, 16));
    mloc = fmaxf(mloc, __shfl_xor(mloc, 32));
    // defer-max: only rescale when some q-row's max grew past m+8
    if (!__all(mloc - m <= 8.f)) {
      const float mn = fmaxf(m, mloc);
      const float r = exp2f((m - mn)*kL2E);
      m = mn;
      l *= r;
      const float rr0 = __shfl(r, hi*4+0), rr1 = __shfl(r, hi*4+1);
      const float rr2 = __shfl(r, hi*4+2), rr3 = __shfl(r, hi*4+3);
      #pragma unroll
      for (int db = 0; db < 4; ++db) {
        acc[db][0] *= rr0; acc[db][1] *= rr1; acc[db][2] *= rr2; acc[db][3] *= rr3;
      }
    }
    float p[8], ls = 0.f;
    #pragma unroll
    for (int t = 0; t < 2; ++t)
      #pragma unroll
      for (int j = 0; j < 4; ++j) {
        const float pv = exp2f((st[t][j] - m)*kL2E);
        p[t*4+j] = pv; ls += pv;
      }
    l += ls;
    // pack P into bf16 pair-words
    const unsigned c00 = pk2(p[0], p[1]);
    const unsigned c01 = pk2(p[2], p[3]);
    const unsigned c10 = pk2(p[4], p[5]);
    const unsigned c11 = pk2(p[6], p[7]);
    // half-wave combine (E/F/G/H), then 16-lane exchange + select
    const unsigned c00x = __shfl_xor((int)c00, 32), c10x = __shfl_xor((int)c10, 32);
    const unsigned c01x = __shfl_xor((int)c01, 32), c11x = __shfl_xor((int)c11, 32);
    const unsigned E = up ? c10x : c00, F = up ? c10 : c00x;
    const unsigned G = up ? c11x : c01, H = up ? c11 : c01x;
    const unsigned Ex = __shfl_xor((int)E, 16), Fx = __shfl_xor((int)F, 16);
    const unsigned Gx = __shfl_xor((int)G, 16), Hx = __shfl_xor((int)H, 16);
    union { unsigned w[4]; s16x8 v; } pa;
    pa.w[0] = subhi ? Fx : E;
    pa.w[1] = subhi ? Hx : G;
    pa.w[2] = subhi ? F  : Ex;
    pa.w[3] = subhi ? H  : Gx;
    #pragma unroll
    for (int db = 0; db < 4; ++db) {
      const u16* vp = Vg + ((size_t)(db*16 + qr))*kM + k0 + hi*8;
      const s16x8 vf = *(const s16x8*)(vp);
      acc[db] = __builtin_amdgcn_mfma_f32_16x16x32_bf16(pa.v, vf, acc[db], 0, 0, 0);
    }
  }
}

// self (CROSSQ=0: Qb [96g][512][64] prescaled) / cross (CROSSQ=1: Qb=[12288][256] raw)
template<int CROSSQ>
__global__ __launch_bounds__(256) void attn_mm_k(
    const u16* __restrict__ Qb, const u16* __restrict__ Kb,
    const u16* __restrict__ Vt, u16* __restrict__ ctx)
{
  const int w = threadIdx.x >> 6, lane = threadIdx.x & 63;
  const int bij = (blockIdx.x & 7)*96 + (blockIdx.x >> 3);   // XCD-bijective, 768
  const int g = bij >> 3, qblk = bij & 7;
  const int h = g & 3, bn = g >> 2;
  const int q0 = qblk*64 + w*16;
  const int qr = lane & 15, hi = lane >> 4;

  s16x8 qf0, qf1;
  if (CROSSQ) {
    const u16* qp = Qb + ((size_t)(bn*kM + q0 + qr))*kD + h*kHD + hi*8;
    qf0 = *(const s16x8*)(qp); qf1 = *(const s16x8*)(qp + 32);
  } else {
    const u16* qp = Qb + ((size_t)g*kM + q0 + qr)*kHD + hi*8;
    qf0 = *(const s16x8*)(qp); qf1 = *(const s16x8*)(qp + 32);
  }

  const u16* Kg = Kb + (size_t)g*kM*kHD;
  const u16* Vg = Vt + (size_t)g*kHD*kM;
  f32x4 acc[4] = {};
  float m = -1e30f, l = 0.f;
  attn_core(Kg, Vg, qf0, qf1, qr, hi, acc, m, l);

  l += __shfl_xor(l, 16); l += __shfl_xor(l, 32);
  const float li = 1.f/l;
  const float l0 = __shfl(li, hi*4+0), l1 = __shfl(li, hi*4+1);
  const float l2 = __shfl(li, hi*4+2), l3 = __shfl(li, hi*4+3);
  #pragma unroll
  for (int db = 0; db < 4; ++db) {
    const size_t base = ((size_t)(bn*kM + q0 + hi*4))*kD + h*kHD + db*16 + qr;
    ctx[base + 0*kD] = f2b(acc[db][0]*l0);
    ctx[base + 1*kD] = f2b(acc[db][1]*l1);
    ctx[base + 2*kD] = f2b(acc[db][2]*l2);
    ctx[base + 3*kD] = f2b(acc[db][3]*l3);
  }
}

__device__ __forceinline__ void rope4(const f32x4 x, const f32x4 e0, const f32x4 e1, float o[4])
{
  o[0] = x[0]*e0[0] - x[1]*e1[0];
  o[1] = x[1]*e0[1] + x[0]*e1[1];
  o[2] = x[2]*e0[2] - x[3]*e1[2];
  o[3] = x[3]*e0[3] + x[2]*e1[3];
}

// s2s: block = (bh, col, qblk, split); split = single (i,j) pair 0..4.
// Writes 0.2-scaled normalized partial (bf16) to ctx5[split].
__global__ __launch_bounds__(256) void attn_s2s_k(
    const float* __restrict__ Qraw, const u16* __restrict__ Kb,
    const u16* __restrict__ Vt, const float* __restrict__ qenc,
    u16* __restrict__ ctx5)
{
  const int w = threadIdx.x >> 6, lane = threadIdx.x & 63;
  const int bij = (blockIdx.x & 7)*240 + (blockIdx.x >> 3);  // 1920; chunk == bh
  const int bh = bij / 240;
  const int rest = bij % 240;
  const int col = rest / 40;
  const int rem = rest % 40;
  const int qblk = rem / 5, split = rem % 5;
  const int q0 = qblk*64 + w*16;
  const int qr = lane & 15, hi = lane >> 4;

  const int e  = split*6 + col;
  const int iv = e/5;
  const int j0 = e%5;
  const int jv = j0 + (j0 >= iv ? 1 : 0);
  s16x8 qf0, qf1;
  {
    const float* qp = Qraw + ((size_t)(bh*kN + jv)*kM + q0 + qr)*kHD + hi*8;
    const float* ep = qenc + ((size_t)(iv*kN + jv))*kHD + hi*8;
    union { u16 u[8]; s16x8 v; } A, B;
    float o[4];
    rope4(*(const f32x4*)(qp),   *(const f32x4*)(ep),   *(const f32x4*)(ep+kQEncSlab), o);
    #pragma unroll
    for (int j = 0; j < 4; ++j) A.u[j] = f2b(o[j]*0.125f);
    rope4(*(const f32x4*)(qp+4), *(const f32x4*)(ep+4), *(const f32x4*)(ep+kQEncSlab+4), o);
    #pragma unroll
    for (int j = 0; j < 4; ++j) A.u[4+j] = f2b(o[j]*0.125f);
    rope4(*(const f32x4*)(qp+32), *(const f32x4*)(ep+32), *(const f32x4*)(ep+kQEncSlab+32), o);
    #pragma unroll
    for (int j = 0; j < 4; ++j) B.u[j] = f2b(o[j]*0.125f);
    rope4(*(const f32x4*)(qp+36), *(const f32x4*)(ep+36), *(const f32x4*)(ep+kQEncSlab+36), o);
    #pragma unroll
    for (int j = 0; j < 4; ++j) B.u[4+j] = f2b(o[j]*0.125f);
    qf0 = A.v; qf1 = B.v;
  }
  const int g2 = bh*kN + iv;
  const u16* Kg = Kb + (size_t)g2*kM*kHD;
  const u16* Vg = Vt + (size_t)g2*kHD*kM;
  f32x4 acc[4] = {};
  float m = -1e30f, l = 0.f;
  attn_core(Kg, Vg, qf0, qf1, qr, hi, acc, m, l);
  l += __shfl_xor(l, 16); l += __shfl_xor(l, 32);
  const float li = 0.2f/l;
  const float l0 = __shfl(li, hi*4+0), l1 = __shfl(li, hi*4+1);
  const float l2 = __shfl(li, hi*4+2), l3 = __shfl(li, hi*4+3);

  const int b = bh >> 2, h = bh & 3;
  u16* outp = ctx5 + (size_t)split*kTOK;
  #pragma unroll
  for (int db = 0; db < 4; ++db) {
    const size_t base = ((size_t)((b*kN + col)*kM + q0 + hi*4))*kD + h*kHD + db*16 + qr;
    outp[base + 0*kD] = f2b(acc[db][0]*l0);
    outp[base + 1*kD] = f2b(acc[db][1]*l1);
    outp[base + 2*kD] = f2b(acc[db][2]*l2);
    outp[base + 3*kD] = f2b(acc[db][3]*l3);
  }
}

__global__ __launch_bounds__(256) void sum5_k(const u16* __restrict__ c5,
                                              u16* __restrict__ outU)
{
  const size_t i4 = ((size_t)blockIdx.x*256 + threadIdx.x)*4;
  float s0=0.f, s1=0.f, s2=0.f, s3=0.f;
  #pragma unroll
  for (int sp = 0; sp < 5; ++sp) {
    uint2 d = *(const uint2*)(c5 + sp*kTOK + i4);
    s0 += b2f((u16)(d.x & 0xffff)); s1 += b2f((u16)(d.x >> 16));
    s2 += b2f((u16)(d.y & 0xffff)); s3 += b2f((u16)(d.y >> 16));
  }
  union { u16 u[4]; uint2 d; } o;
  o.u[0]=f2b(s0); o.u[1]=f2b(s1); o.u[2]=f2b(s2); o.u[3]=f2b(s3);
  *(uint2*)(outU + i4) = o.d;
}

// t2t attention: wave per (b,h,nq,m) — 24576 waves.
__global__ __launch_bounds__(256) void attn_t2t_k(
    const u16* __restrict__ qkvU, u16* __restrict__ ctxU)
{
  const int wid = blockIdx.x*4 + (threadIdx.x >> 6);
  const int lane = threadIdx.x & 63;
  const int m = wid & 511;
  const int t = wid >> 9;
  const int nq = t % kN;
  const int bh = t / kN;
  const int h = bh & 3, b = bh >> 2;
  const u16* pb[kN];
  #pragma unroll
  for (int nk = 0; nk < kN; ++nk)
    pb[nk] = qkvU + ((size_t)(b*kN+nk)*kM + m)*768 + h*192;
  const float qc = b2f(pb[nq][lane*3]);
  float sim[kN];
  #pragma unroll
  for (int nk = 0; nk < kN; ++nk)
    sim[nk] = wred_sum(qc * b2f(pb[nk][lane*3+1])) * 0.125f;
  float mx = sim[0];
  #pragma unroll
  for (int nk = 1; nk < kN; ++nk) mx = fmaxf(mx, sim[nk]);
  float p[kN], s = 0.f;
  #pragma unroll
  for (int nk = 0; nk < kN; ++nk) { p[nk] = expf(sim[nk]-mx); s += p[nk]; }
  const float inv = 1.f/s;
  float o = 0.f;
  #pragma unroll
  for (int nk = 0; nk < kN; ++nk) o = fmaf(p[nk], b2f(pb[nk][lane*3+2]), o);
  ctxU[((size_t)(b*kN+nq)*kM + m)*kD + h*kHD + lane] = f2b(o*inv);
}

// LayerNorm(512) + exact GELU: reads f32, writes bf16 (separate buffer).
__global__ __launch_bounds__(256) void lngelu_k(
    const float* __restrict__ x, u16* __restrict__ y,
    const float* __restrict__ g0, const float* __restrict__ b0,
    const float* __restrict__ g1, const float* __restrict__ b1, int Mh)
{
  const int row = blockIdx.x;
  const int tid = threadIdx.x;
  const float* g = (row < Mh) ? g0 : g1;
  const float* bb = (row < Mh) ? b0 : b1;
  const float* xr = x + (size_t)row*512;
  const float v0 = xr[tid], v1 = xr[tid+256];
  const int w = tid >> 6, lane = tid & 63;
  __shared__ float red[2][4];
  const float s1 = wred_sum(v0+v1);
  const float s2 = wred_sum(v0*v0+v1*v1);
  if (lane == 0){ red[0][w]=s1; red[1][w]=s2; }
  __syncthreads();
  const float mean = (red[0][0]+red[0][1]+red[0][2]+red[0][3]) * (1.f/512.f);
  const float ms   = (red[1][0]+red[1][1]+red[1][2]+red[1][3]) * (1.f/512.f);
  const float rs = rsqrtf(ms - mean*mean + 1e-5f);
  const float y0 = (v0-mean)*rs*g[tid]     + bb[tid];
  const float y1 = (v1-mean)*rs*g[tid+256] + bb[tid+256];
  y[(size_t)row*512 + tid]     = f2b(0.5f*y0*(1.f+erff(y0*0.70710678118654752f)));
  y[(size_t)row*512 + tid+256] = f2b(0.5f*y1*(1.f+erff(y1*0.70710678118654752f)));
}

__global__ void conf_dot_k(const float* __restrict__ tmp, const float* __restrict__ w2,
                           const float* __restrict__ b2, float* __restrict__ out)
{
  const int w = threadIdx.x >> 6, lane = threadIdx.x & 63;
  const int row = blockIdx.x*4 + w;
  const float* t = tmp + (size_t)row*kD;
  float s = 0.f;
  #pragma unroll
  for (int j=0;j<4;++j) s = fmaf(t[lane+j*64], w2[lane+j*64], s);
  s = wred_sum(s);
  if (lane == 0) out[row] = s + b2[0];
}

// ---------------------------------------------------------------------------
extern "C" void kernel_launch(void* const* d_in, const int* in_sizes, int n_in,
                              void* d_out, int out_size, void* d_ws, size_t ws_size,
                              hipStream_t stream)
{
  auto F = [&](int i){ return (const float*)d_in[i]; };
  const float* t_desc = F(0);
  const float* s_desc = F(1);
  const float* t_enc  = F(2);
  const float* s_enc  = F(3);
  const float* q_enc  = F(4);
  const float* k_enc  = F(5);

  // ---- workspace map ----
  char* base = (char*)d_ws;
  float* xts = (float*)base;                     // 12288x256 f32 (xt|xs)
  float* xt = xts;
  float* xs = xts + kTOK;
  char* R1  = base + 2*kTOK*sizeof(float);       // 25.17 MB multi-use
  char* CTX = R1 + 4*kTOK*sizeof(float);         // 6.29 MB
  char* MSG = CTX + 2*kTOK*sizeof(u16);          // 6.29 MB
  u16* Qb16 = (u16*)(MSG + kTOK*sizeof(float));  // 96x512x64
  u16* Kb16 = Qb16 + 2*kTOK;
  u16* Vt16 = Kb16 + 2*kTOK;
  u16* wsW  = Vt16 + 2*kTOK;
  // aliases
  u16*   qkvU  = (u16*)R1;                       // 12288x768
  u16*   qU    = (u16*)R1;                       // 12288x256 (cross q)
  u16*   kvU   = (u16*)R1 + (size_t)kRows*kD;    // 12288x512 (cross kv)
  float* hbuf  = (float*)R1;                     // 12288x512 f32
  u16*   ctx5  = (u16*)R1;                       // 5 x 6144x256 bf16 (s2s partials)
  u16*   ctxU  = (u16*)CTX;                      // 12288x256
  u16*   msgU  = (u16*)MSG;                      // 12288x256
  float* Qs2s  = (float*)MSG;                    // 48x512x64 f32
  float* confb = (float*)MSG;                    // 6144x256 f32
  u16*   yU    = (u16*)CTX;                      // 12288x512 (spans CTX+MSG)

  float* out_t2s2 = (float*)d_out;               // rows 0..12287 (t2|s2)
  float* out_conf = (float*)d_out + 2*kTOK;

  // ---- weight transpose+cast table ----
  WtTable tab;
  int nd = 0, total_tiles = 0;
  size_t woff = 0;
  const u16* wp[18];
  auto addw = [&](int idx, int K, int N){
    u16* dst = wsW + woff;
    tab.d[nd] = { F(idx), dst, K, N, (K>>5)*(N>>5) };
    total_tiles += tab.d[nd].ntiles;
    wp[nd] = dst;
    woff += (size_t)K*N;
    ++nd;
    return nd-1;
  };
  const int W_SA_QKV = addw(6, 256, 768);
  const int W_SA_OUT = addw(8, 256, 256);
  const int W_SA_F1  = addw(10, 512, 512);
  const int W_SA_F2  = addw(14, 512, 256);
  const int W_SS_QKV = addw(16, 256, 768);
  const int W_SS_OUT = addw(18, 256, 256);
  const int W_SS_F1  = addw(20, 512, 512);
  const int W_SS_F2  = addw(24, 512, 256);
  const int W_TT_QKV = addw(26, 256, 768);
  const int W_TT_OUT = addw(28, 256, 256);
  const int W_TT_F1  = addw(30, 512, 512);
  const int W_TT_F2  = addw(34, 512, 256);
  const int W_CA_Q   = addw(36, 256, 256);
  const int W_CA_KV  = addw(38, 256, 512);
  const int W_CA_OUT = addw(40, 256, 256);
  const int W_CA_F1  = addw(42, 512, 512);
  const int W_CA_F2  = addw(46, 512, 256);
  const int W_CF_1   = addw(48, 256, 256);
  wtcast_k<<<total_tiles, 256, 0, stream>>>(tab);

  // mmad launchers (dual row-segment, 12288 rows unless noted)
  auto mm_f32_to_b16 = [&](const float* a1a, const float* a1b, int wa, int wb2,
                           const float* ba, const float* bb2, u16* c, int N_, int K_){
    dim3 grid(N_/128, kRows/128);
    mmad_k<false,false,true><<<grid,256,0,stream>>>(a1a, a1b, nullptr, nullptr, K_,
        wp[wa], wp[wb2], ba, bb2, nullptr, nullptr, c, N_, K_, kRowsH, 0);
  };
  auto mm_b16_to_b16 = [&](const u16* a1a, const u16* a1b, int wa, int wb2,
                           const float* ba, const float* bb2, u16* c, int N_, int K_){
    dim3 grid(N_/128, kRows/128);
    mmad_k<true,false,true><<<grid,256,0,stream>>>(a1a, a1b, nullptr, nullptr, K_,
        wp[wa], wp[wb2], ba, bb2, nullptr, nullptr, c, N_, K_, kRowsH, 0);
  };
  auto mm_f1 = [&](const float* a1a, const float* a1b, const u16* a2a, const u16* a2b,
                   int wa, int wb2, const float* ba, const float* bb2, float* c){
    dim3 grid(512/128, kRows/128);
    mmad_k<false,true,false><<<grid,256,0,stream>>>(a1a, a1b, a2a, a2b, 256,
        wp[wa], wp[wb2], ba, bb2, nullptr, nullptr, c, 512, 512, kRowsH, 0);
  };
  auto mm_f2 = [&](const u16* a1a, const u16* a1b, int wa, int wb2,
                   const float* ba, const float* bb2,
                   const float* ra, const float* rb, float* c){
    dim3 grid(256/128, kRows/128);
    mmad_k<true,false,false><<<grid,256,0,stream>>>(a1a, a1b, nullptr, nullptr, 512,
        wp[wa], wp[wb2], ba, bb2, ra, rb, c, 256, 512, kRowsH, 0);
  };

  // ================= SELF (t || s, shared sa weights) =================
  mm_f32_to_b16(t_desc, s_desc, W_SA_QKV, W_SA_QKV, F(7), F(7), qkvU, 768, 256);
  prep_self_k<<<kGrp*8, 256, 0, stream>>>(qkvU, t_enc, s_enc, Qb16, Kb16, Vt16);
  attn_mm_k<0><<<kGrp*8, 256, 0, stream>>>(Qb16, Kb16, Vt16, ctxU);
  mm_b16_to_b16(ctxU, ctxU + kTOK, W_SA_OUT, W_SA_OUT, F(9), F(9), msgU, 256, 256);
  mm_f1(t_desc, s_desc, msgU, msgU + kTOK, W_SA_F1, W_SA_F1, F(11), F(11), hbuf);
  lngelu_k<<<kRows, 256, 0, stream>>>(hbuf, yU, F(12), F(13), F(12), F(13), kRowsH);
  mm_f2(yU, yU + (size_t)kRowsH*512, W_SA_F2, W_SA_F2, F(15), F(15), t_desc, s_desc, xts);

  // ================= TT (t) || SS (s) =================
  mm_f32_to_b16(xt, xs, W_TT_QKV, W_SS_QKV, F(27), F(17), qkvU, 768, 256);
  prep_s2s_k<<<kGrpH*8, 256, 0, stream>>>(qkvU, k_enc, Qs2s, Kb16, Vt16);
  attn_t2t_k<<<(kB*kH*kN*kM)/4, 256, 0, stream>>>(qkvU, ctxU);
  attn_s2s_k<<<1920, 256, 0, stream>>>(Qs2s, Kb16, Vt16, q_enc, ctx5);
  sum5_k<<<(int)(kTOK/1024), 256, 0, stream>>>(ctx5, ctxU + kTOK);
  mm_b16_to_b16(ctxU, ctxU + kTOK, W_TT_OUT, W_SS_OUT, F(29), F(19), msgU, 256, 256);
  mm_f1(xt, xs, msgU, msgU + kTOK, W_TT_F1, W_SS_F1, F(31), F(21), hbuf);
  lngelu_k<<<kRows, 256, 0, stream>>>(hbuf, yU, F(32), F(33), F(22), F(23), kRowsH);
  mm_f2(yU, yU + (size_t)kRowsH*512, W_TT_F2, W_SS_F2, F(35), F(25), xt, xs, xts);

  // ================= CONF (from xs post-s2s) =================
  {
    dim3 grid(2, kRowsH/128);
    mmad_k<false,false,false><<<grid,256,0,stream>>>(xs, xs, nullptr, nullptr, 256,
        wp[W_CF_1], wp[W_CF_1], F(49), F(49), nullptr, nullptr, confb, 256, 256, kRowsH, 1);
  }
  conf_dot_k<<<kRowsH/4, 256, 0, stream>>>(confb, F(50), F(51), out_conf);

  // ================= CROSS (t2: q=xt,kv=xs || s2: q=xs,kv=xt) =================
  mm_f32_to_b16(xt, xs, W_CA_Q, W_CA_Q, F(37), F(37), qU, 256, 256);
  mm_f32_to_b16(xs, xt, W_CA_KV, W_CA_KV, F(39), F(39), kvU, 512, 256);
  prep_cross_k<<<kGrp*8, 256, 0, stream>>>(kvU, Kb16, Vt16);
  attn_mm_k<1><<<kGrp*8, 256, 0, stream>>>(qU, Kb16, Vt16, ctxU);
  mm_b16_to_b16(ctxU, ctxU + kTOK, W_CA_OUT, W_CA_OUT, F(41), F(41), msgU, 256, 256);
  mm_f1(xt, xs, msgU, msgU + kTOK, W_CA_F1, W_CA_F1, F(43), F(43), hbuf);
  lngelu_k<<<kRows, 256, 0, stream>>>(hbuf, yU, F(44), F(45), F(44), F(45), kRowsH);
  mm_f2(yU, yU + (size_t)kRowsH*512, W_CA_F2, W_CA_F2, F(47), F(47), xt, xs, out_t2s2);
}